// Round 6
// baseline (162.986 us; speedup 1.0000x reference)
//
#include <hip/hip_runtime.h>
#include <math.h>

typedef unsigned short ushort;
typedef __attribute__((ext_vector_type(8))) short bf16x8;
typedef __attribute__((ext_vector_type(4))) float f32x4;

#define MFMA16(a, b, c) __builtin_amdgcn_mfma_f32_16x16x32_bf16(a, b, c, 0, 0, 0)
#define GLOAD16(g, l)                                                   \
  __builtin_amdgcn_global_load_lds(                                     \
      (const __attribute__((address_space(1))) unsigned int*)(g),       \
      (__attribute__((address_space(3))) unsigned int*)(l), 16, 0, 0)

__device__ __forceinline__ ushort f2bf(float f) {
  unsigned u = __float_as_uint(f);
  u += 0x7FFFu + ((u >> 16) & 1u);  // RNE
  return (ushort)(u >> 16);
}
__device__ __forceinline__ float bf2f(ushort b) {
  return __uint_as_float(((unsigned)b) << 16);
}

// ---------------------------------------------------------------------------
// Split fp32 -> (hi, lo) bf16 pair.  n4 = element_count/4.
// ---------------------------------------------------------------------------
__global__ __launch_bounds__(256) void split_kernel(
    const float* __restrict__ in, ushort* __restrict__ hi,
    ushort* __restrict__ lo, int n4) {
  int i = blockIdx.x * 256 + threadIdx.x;
  if (i >= n4) return;
  float4 v = ((const float4*)in)[i];
  ushort4 h, l;
  h.x = f2bf(v.x); l.x = f2bf(v.x - bf2f(h.x));
  h.y = f2bf(v.y); l.y = f2bf(v.y - bf2f(h.y));
  h.z = f2bf(v.z); l.z = f2bf(v.z - bf2f(h.z));
  h.w = f2bf(v.w); l.w = f2bf(v.w - bf2f(h.w));
  ((ushort4*)hi)[i] = h;
  ((ushort4*)lo)[i] = l;
}

// ---------------------------------------------------------------------------
// Fused weight prep: 4 weight splits (hi/lo bf16) + dw transpose, one launch.
// ---------------------------------------------------------------------------
__global__ __launch_bounds__(256) void prep_weights(
    const float* __restrict__ q_w, const float* __restrict__ k_w,
    const float* __restrict__ v_w, const float* __restrict__ o_w,
    const float* __restrict__ dw_w, ushort* __restrict__ Wqh,
    ushort* __restrict__ Wql, ushort* __restrict__ Wkh,
    ushort* __restrict__ Wkl, ushort* __restrict__ Wvh,
    ushort* __restrict__ Wvl, ushort* __restrict__ Woh,
    ushort* __restrict__ Wol, float* __restrict__ dwT) {
  int blk = blockIdx.x;
  if (blk < 1024) {
    int grp = blk >> 8;
    const float* in = grp == 0 ? q_w : grp == 1 ? k_w : grp == 2 ? v_w : o_w;
    ushort* hi = grp == 0 ? Wqh : grp == 1 ? Wkh : grp == 2 ? Wvh : Woh;
    ushort* lo = grp == 0 ? Wql : grp == 1 ? Wkl : grp == 2 ? Wvl : Wol;
    int i = (blk & 255) * 256 + threadIdx.x;
    float4 v = ((const float4*)in)[i];
    ushort4 h, l;
    h.x = f2bf(v.x); l.x = f2bf(v.x - bf2f(h.x));
    h.y = f2bf(v.y); l.y = f2bf(v.y - bf2f(h.y));
    h.z = f2bf(v.z); l.z = f2bf(v.z - bf2f(h.z));
    h.w = f2bf(v.w); l.w = f2bf(v.w - bf2f(h.w));
    ((ushort4*)hi)[i] = h;
    ((ushort4*)lo)[i] = l;
  } else {
    int c = (blk - 1024) * 256 + threadIdx.x;
    #pragma unroll
    for (int k = 0; k < 25; ++k) dwT[k * 512 + c] = dw_w[c * 25 + k];
  }
}

// ---------------------------------------------------------------------------
// MFMA GEMM body (shared by fused-QKV and O-proj): Y[.,512]=A@W^T+b, 3-pass.
// ---------------------------------------------------------------------------
__device__ __forceinline__ void gemm_body(
    const ushort* __restrict__ Ahi, const ushort* __restrict__ Alo,
    const ushort* __restrict__ Bhi, const ushort* __restrict__ Blo,
    const float* __restrict__ bias, float* __restrict__ Y,
    int m0, int n0, ushort* lds) {
  ushort* sAhi = lds;
  ushort* sAlo = lds + 8192;
  ushort* sBhi = lds + 16384;
  ushort* sBlo = lds + 20480;
  int tid = threadIdx.x;
  int lane = tid & 63;
  int w = tid >> 6;
  int wr = (w >> 1) * 64;
  int wc = (w & 1) * 32;
  int l8r = lane >> 3;
  int sll = ((lane & 7) ^ l8r) << 3;
  int l16 = lane & 15, lq = lane >> 4;

  f32x4 acc[4][2];
  f32x4 zero = {0.f, 0.f, 0.f, 0.f};
  #pragma unroll
  for (int m = 0; m < 4; ++m)
    #pragma unroll
    for (int n = 0; n < 2; ++n) acc[m][n] = zero;

  for (int kt = 0; kt < 8; ++kt) {
    int kk = kt * 64;
    __syncthreads();
    #pragma unroll
    for (int q = 0; q < 4; ++q) {
      int ci = w * 4 + q;
      size_t go = (size_t)(m0 + ci * 8 + l8r) * 512 + kk + sll;
      GLOAD16(Ahi + go, sAhi + ci * 512);
      GLOAD16(Alo + go, sAlo + ci * 512);
    }
    #pragma unroll
    for (int q = 0; q < 2; ++q) {
      int ci = w * 2 + q;
      size_t go = (size_t)(n0 + ci * 8 + l8r) * 512 + kk + sll;
      GLOAD16(Bhi + go, sBhi + ci * 512);
      GLOAD16(Blo + go, sBlo + ci * 512);
    }
    __syncthreads();
    #pragma unroll
    for (int ks = 0; ks < 2; ++ks) {
      int slot = ks * 4 + lq;
      bf16x8 ah[4], al[4], bh[2], bl[2];
      #pragma unroll
      for (int m = 0; m < 4; ++m) {
        int r = wr + m * 16 + l16;
        int ph = (slot ^ (r & 7)) << 3;
        ah[m] = *(const bf16x8*)&sAhi[r * 64 + ph];
        al[m] = *(const bf16x8*)&sAlo[r * 64 + ph];
      }
      #pragma unroll
      for (int n = 0; n < 2; ++n) {
        int r = wc + n * 16 + l16;
        int ph = (slot ^ (r & 7)) << 3;
        bh[n] = *(const bf16x8*)&sBhi[r * 64 + ph];
        bl[n] = *(const bf16x8*)&sBlo[r * 64 + ph];
      }
      #pragma unroll
      for (int m = 0; m < 4; ++m)
        #pragma unroll
        for (int n = 0; n < 2; ++n) {
          acc[m][n] = MFMA16(ah[m], bh[n], acc[m][n]);
          acc[m][n] = MFMA16(ah[m], bl[n], acc[m][n]);
          acc[m][n] = MFMA16(al[m], bh[n], acc[m][n]);
        }
    }
  }
  #pragma unroll
  for (int n = 0; n < 2; ++n) {
    int col = n0 + wc + n * 16 + l16;
    float bv = bias[col];
    #pragma unroll
    for (int m = 0; m < 4; ++m) {
      #pragma unroll
      for (int j = 0; j < 4; ++j) {
        int row = m0 + wr + m * 16 + lq * 4 + j;
        Y[(size_t)row * 512 + col] = acc[m][n][j] + bv;
      }
    }
  }
}

__global__ __launch_bounds__(256) void gemm_qkv(
    const ushort* __restrict__ Ahi, const ushort* __restrict__ Alo,
    const ushort* __restrict__ Wh0, const ushort* __restrict__ Wl0,
    const ushort* __restrict__ Wh1, const ushort* __restrict__ Wl1,
    const ushort* __restrict__ Wh2, const ushort* __restrict__ Wl2,
    const float* __restrict__ b0, const float* __restrict__ b1,
    const float* __restrict__ b2, float* __restrict__ Y0,
    float* __restrict__ Y1, float* __restrict__ Y2) {
  __shared__ ushort lds[24576];
  int which = blockIdx.x >> 3;
  int n0 = (blockIdx.x & 7) * 64;
  int m0 = blockIdx.y * 128;
  const ushort* Bh; const ushort* Bl; const float* bb; float* Y;
  if (which == 0)      { Bh = Wh0; Bl = Wl0; bb = b0; Y = Y0; }
  else if (which == 1) { Bh = Wh1; Bl = Wl1; bb = b1; Y = Y1; }
  else                 { Bh = Wh2; Bl = Wl2; bb = b2; Y = Y2; }
  gemm_body(Ahi, Alo, Bh, Bl, bb, Y, m0, n0, lds);
}

__global__ __launch_bounds__(256) void gemm_mfma(
    const ushort* __restrict__ Ahi, const ushort* __restrict__ Alo,
    const ushort* __restrict__ Bhi, const ushort* __restrict__ Blo,
    const float* __restrict__ bias, float* __restrict__ Y) {
  __shared__ ushort lds[24576];
  gemm_body(Ahi, Alo, Bhi, Blo, bias, Y, blockIdx.y * 128, blockIdx.x * 64, lds);
}

// ---------------------------------------------------------------------------
// Offset network v2 (register sliding-window depthwise conv).
// ---------------------------------------------------------------------------
__global__ __launch_bounds__(256) void offset_net2(
    const float* __restrict__ x, const float* __restrict__ dwT,
    const float* __restrict__ dw_b, const float* __restrict__ off_w,
    float* __restrict__ samp) {
  __shared__ float wT[16][516];
  __shared__ float hT[16][516];
  __shared__ float ofs[16][16];
  int x0 = blockIdx.x * 16;
  int y = blockIdx.y;
  int b = blockIdx.z;
  int tid = threadIdx.x;

  for (int e = tid; e < 2048; e += 256) {
    int o = e >> 7, c4 = e & 127;
    *(float4*)&wT[o][c4 * 4] = *(const float4*)&off_w[o * 512 + c4 * 4];
  }

  int c = tid * 2;
  float2 dwv[25];
  #pragma unroll
  for (int k = 0; k < 25; ++k) dwv[k] = *(const float2*)&dwT[k * 512 + c];
  float2 cb = *(const float2*)&dw_b[c];

  const float* xb = x + (size_t)b * 1024 * 512 + c;
  bool rv[5];
  #pragma unroll
  for (int r = 0; r < 5; ++r) {
    int yy = y - 2 + r;
    rv[r] = (yy >= 0 && yy < 32);
  }
  float2 win[5][5];
  #pragma unroll
  for (int j = 0; j < 4; ++j) {
    int xc = x0 - 2 + j;
    bool cvld = (xc >= 0 && xc < 32);
    #pragma unroll
    for (int r = 0; r < 5; ++r) {
      win[r][j] = (rv[r] && cvld)
          ? *(const float2*)&xb[(size_t)((y - 2 + r) * 32 + xc) * 512]
          : make_float2(0.f, 0.f);
    }
  }
  #pragma unroll
  for (int i = 0; i < 16; ++i) {
    int xc = x0 + i + 2;
    bool cvld = (xc < 32);
    #pragma unroll
    for (int r = 0; r < 5; ++r) {
      win[r][4] = (rv[r] && cvld)
          ? *(const float2*)&xb[(size_t)((y - 2 + r) * 32 + xc) * 512]
          : make_float2(0.f, 0.f);
    }
    float sx = cb.x, sy = cb.y;
    #pragma unroll
    for (int r = 0; r < 5; ++r)
      #pragma unroll
      for (int j = 0; j < 5; ++j) {
        sx += win[r][j].x * dwv[r * 5 + j].x;
        sy += win[r][j].y * dwv[r * 5 + j].y;
      }
    float g0 = 0.5f * sx * (1.0f + erff(sx * 0.70710678118654752f));
    float g1 = 0.5f * sy * (1.0f + erff(sy * 0.70710678118654752f));
    *(float2*)&hT[i][c] = make_float2(g0, g1);
    #pragma unroll
    for (int r = 0; r < 5; ++r) {
      win[r][0] = win[r][1]; win[r][1] = win[r][2];
      win[r][2] = win[r][3]; win[r][3] = win[r][4];
    }
  }
  __syncthreads();

  {
    int o = tid & 15, px = tid >> 4;
    float acc = 0.f;
    #pragma unroll 4
    for (int c4 = 0; c4 < 128; ++c4) {
      float4 hv = *(const float4*)&hT[px][c4 * 4];
      float4 wv = *(const float4*)&wT[o][c4 * 4];
      acc += hv.x * wv.x + hv.y * wv.y + hv.z * wv.z + hv.w * wv.w;
    }
    ofs[px][o] = tanhf(acc) * 2.0f;
  }
  __syncthreads();

  if (tid < 128) {
    int px = tid >> 3, h = tid & 7;
    int n = y * 32 + x0 + px;
    float gx = -1.0f + 2.0f * (float)(x0 + px) / 31.0f;
    float gy = -1.0f + 2.0f * (float)y / 31.0f;
    float sx = fminf(fmaxf(gx + ofs[px][2 * h], -1.0f), 1.0f);
    float sy = fminf(fmaxf(gy + ofs[px][2 * h + 1], -1.0f), 1.0f);
    float2 pc;
    pc.x = (sx + 1.0f) * 16.0f - 0.5f;
    pc.y = (sy + 1.0f) * 16.0f - 0.5f;
    ((float2*)samp)[(size_t)(b * 8 + h) * 1024 + n] = pc;
  }
}

// ---------------------------------------------------------------------------
// Bilinear grid-sample of K and V -> Ks hi/lo [bh][1024][64], Vt [bh][64][1024]
// ---------------------------------------------------------------------------
__global__ __launch_bounds__(256) void grid_sample(
    const float* __restrict__ K, const float* __restrict__ V,
    const float* __restrict__ samp, ushort* __restrict__ Ksh,
    ushort* __restrict__ Ksl, ushort* __restrict__ Vt) {
  __shared__ ushort sV[64][72];
  int bh = blockIdx.y;
  int b = bh >> 3, h = bh & 7;
  int jb = blockIdx.x;
  int d = threadIdx.x & 63;
  for (int p = 0; p < 16; ++p) {
    int jl = p * 4 + (threadIdx.x >> 6);
    int j = jb * 64 + jl;
    float2 pc = ((const float2*)samp)[(size_t)bh * 1024 + j];
    float gx = pc.x, gy = pc.y;
    float x0 = floorf(gx), y0 = floorf(gy);
    float aK = 0.f, aV = 0.f;
    #pragma unroll
    for (int dy = 0; dy < 2; ++dy)
      #pragma unroll
      for (int dx = 0; dx < 2; ++dx) {
        float xi = x0 + (float)dx, yi = y0 + (float)dy;
        float wgt = (1.0f - fabsf(gx - xi)) * (1.0f - fabsf(gy - yi));
        if (xi >= 0.f && xi < 32.f && yi >= 0.f && yi < 32.f) {
          size_t base = ((size_t)b * 1024 + (int)yi * 32 + (int)xi) * 512 + h * 64 + d;
          aK += K[base] * wgt;
          aV += V[base] * wgt;
        }
      }
    ushort kh = f2bf(aK);
    size_t o = ((size_t)bh * 1024 + j) * 64 + d;
    Ksh[o] = kh;
    Ksl[o] = f2bf(aK - bf2f(kh));
    sV[jl][d] = f2bf(aV);
  }
  __syncthreads();
  int dd = threadIdx.x >> 2, c4 = threadIdx.x & 3;
  bf16x8 v0, v1;
  #pragma unroll
  for (int k = 0; k < 8; ++k) v0[k] = (short)sV[c4 * 16 + k][dd];
  #pragma unroll
  for (int k = 0; k < 8; ++k) v1[k] = (short)sV[c4 * 16 + 8 + k][dd];
  size_t o = ((size_t)bh * 64 + dd) * 1024 + jb * 64 + c4 * 16;
  *(bf16x8*)&Vt[o] = v0;
  *(bf16x8*)&Vt[o + 8] = v1;
}

// ---------------------------------------------------------------------------
// Bicubic taps (64 -> 1024 upsample, half-pixel, border-replicate).
// ---------------------------------------------------------------------------
__device__ __forceinline__ void bicubic_taps(int i, float* w, int* idx) {
  const float a = -0.75f;
  float src = ((float)i + 0.5f) * 0.0625f - 0.5f;
  float fi = floorf(src);
  int i0 = (int)fi;
  float t = src - fi;
  #pragma unroll
  for (int k = -1; k <= 2; ++k) {
    float d = fabsf(t - (float)k);
    float wv;
    if (d <= 1.0f)
      wv = ((a + 2.0f) * d - (a + 3.0f)) * d * d + 1.0f;
    else if (d < 2.0f)
      wv = a * (((d - 5.0f) * d + 8.0f) * d - 4.0f);
    else
      wv = 0.0f;
    int ic = i0 + k;
    ic = ic < 0 ? 0 : (ic > 63 ? 63 : ic);
    w[k + 1] = wv;
    idx[k + 1] = ic;
  }
}

// ---------------------------------------------------------------------------
// G = bias0 @ M^T : [64 src-rows][1024 cols]. 256 KB, L2-resident.
// bias(i,j) is then sum_ka wA_i[ka] * G[iA_i[ka]][j]  (computed in attn).
// ---------------------------------------------------------------------------
__global__ __launch_bounds__(256) void g_kernel(
    const float* __restrict__ table, float* __restrict__ G) {
  __shared__ float tab[225];
  int p = blockIdx.x;  // 0..63
  int tid = threadIdx.x;
  if (tid < 225) tab[tid] = table[tid];
  __syncthreads();
  int py = p >> 3, px = p & 7;
  for (int j = tid; j < 1024; j += 256) {
    float wB[4]; int iB[4];
    bicubic_taps(j, wB, iB);
    float sum = 0.f;
    #pragma unroll
    for (int kb = 0; kb < 4; ++kb) {
      int qb = iB[kb];
      int qy = qb >> 3, qx = qb & 7;
      sum += wB[kb] * tab[(py - qy + 7) * 15 + (px - qx + 7)];
    }
    G[p * 1024 + j] = sum;
  }
}

// ---------------------------------------------------------------------------
// MFMA flash attention v3: XCD-swizzled grid (all 16 i-tiles of a bh on one
// XCD -> K/V L2-resident), bias reconstructed from G (4-tap row combine),
// Q in registers, K/V LDS double-buffered, one barrier per KV-tile.
// ---------------------------------------------------------------------------
__global__ __launch_bounds__(256) void attn_mfma(
    const float* __restrict__ Q, const ushort* __restrict__ Kh,
    const ushort* __restrict__ Kl, const ushort* __restrict__ Vt,
    const float* __restrict__ G, ushort* __restrict__ Oh,
    ushort* __restrict__ Ol) {
  __shared__ ushort sKh[2][4096];
  __shared__ ushort sKl[2][4096];
  __shared__ ushort sVt[2][4096];
  __shared__ ushort sP[4][1152];

  int tid = threadIdx.x;
  int lane = tid & 63;
  int w = tid >> 6;
  int l16 = lane & 15, lq = lane >> 4;
  // XCD-aware decode: blk%8 -> XCD; 4 bh + 16 i-tiles per XCD.
  int blk = blockIdx.x;
  int xcd = blk & 7;
  int rr = blk >> 3;
  int bh = ((rr & 3) << 3) + xcd;
  int i0 = (rr >> 2) * 64;
  int b = bh >> 3, h = bh & 7;
  int r8 = lane >> 3, ch = lane & 7;

  // Q fragments (this wave's 16 rows) straight into registers, *0.125
  bf16x8 qh[2], ql[2];
  #pragma unroll
  for (int s = 0; s < 2; ++s) {
    const float* qp =
        Q + ((size_t)b * 1024 + i0 + w * 16 + l16) * 512 + h * 64 + s * 32 + lq * 8;
    #pragma unroll
    for (int j = 0; j < 8; ++j) {
      float f = qp[j] * 0.125f;
      ushort hb = f2bf(f);
      qh[s][j] = (short)hb;
      ql[s][j] = (short)f2bf(f - bf2f(hb));
    }
  }

  // per-row bicubic taps for bias reconstruction (rows lq*4 + r of my quad)
  float wAr[4][4];
  int iAo[4][4];
  #pragma unroll
  for (int r = 0; r < 4; ++r) {
    float wt[4]; int ix[4];
    bicubic_taps(i0 + w * 16 + lq * 4 + r, wt, ix);
    #pragma unroll
    for (int ka = 0; ka < 4; ++ka) {
      wAr[r][ka] = wt[ka];
      iAo[r][ka] = ix[ka] << 10;
    }
  }

  f32x4 oacc[4];
  f32x4 zero = {0.f, 0.f, 0.f, 0.f};
  #pragma unroll
  for (int n = 0; n < 4; ++n) oacc[n] = zero;
  float mrow[4], lrow[4];
  #pragma unroll
  for (int r = 0; r < 4; ++r) { mrow[r] = -INFINITY; lrow[r] = 0.f; }

  ushort* myP = sP[w];
  int stgrow0 = w * 16;      // this wave stages rows [w*16, w*16+16)
  int grow0 = stgrow0 + r8;  // + q*8

  // ---- prologue: stage tile 0 into buf 0; compute bias(0) ----
  #pragma unroll
  for (int q = 0; q < 2; ++q) {
    int row = grow0 + q * 8;
    int gch = ch ^ (row & 7);
    size_t gk = ((size_t)bh * 1024 + row) * 64 + gch * 8;
    GLOAD16(Kh + gk, &sKh[0][(stgrow0 + q * 8) * 64]);
    GLOAD16(Kl + gk, &sKl[0][(stgrow0 + q * 8) * 64]);
    size_t gv = ((size_t)bh * 64 + row) * 1024 + gch * 8;
    GLOAD16(Vt + gv, &sVt[0][(stgrow0 + q * 8) * 64]);
  }
  f32x4 bias_c[4];
  #pragma unroll
  for (int n = 0; n < 4; ++n) {
    int col = n * 16 + l16;
    #pragma unroll
    for (int r = 0; r < 4; ++r) {
      float s = wAr[r][0] * G[iAo[r][0] + col] + wAr[r][1] * G[iAo[r][1] + col] +
                wAr[r][2] * G[iAo[r][2] + col] + wAr[r][3] * G[iAo[r][3] + col];
      bias_c[n][r] = s;
    }
  }
  __syncthreads();

  int cur = 0;
  for (int jt = 0; jt < 16; ++jt) {
    // ---- issue stage of tile jt+1 into the other buffer ----
    if (jt < 15) {
      #pragma unroll
      for (int q = 0; q < 2; ++q) {
        int row = grow0 + q * 8;
        int gch = ch ^ (row & 7);
        size_t gk = ((size_t)bh * 1024 + (jt + 1) * 64 + row) * 64 + gch * 8;
        GLOAD16(Kh + gk, &sKh[cur ^ 1][(stgrow0 + q * 8) * 64]);
        GLOAD16(Kl + gk, &sKl[cur ^ 1][(stgrow0 + q * 8) * 64]);
        size_t gv = ((size_t)bh * 64 + row) * 1024 + (jt + 1) * 64 + gch * 8;
        GLOAD16(Vt + gv, &sVt[cur ^ 1][(stgrow0 + q * 8) * 64]);
      }
    }
    // consume precomputed bias; compute next tile's bias from G (L2/L1-hot)
    f32x4 sacc[4];
    #pragma unroll
    for (int n = 0; n < 4; ++n) sacc[n] = bias_c[n];
    if (jt < 15) {
      int colb = (jt + 1) * 64 + l16;
      #pragma unroll
      for (int n = 0; n < 4; ++n) {
        int col = colb + n * 16;
        #pragma unroll
        for (int r = 0; r < 4; ++r) {
          float s = wAr[r][0] * G[iAo[r][0] + col] + wAr[r][1] * G[iAo[r][1] + col] +
                    wAr[r][2] * G[iAo[r][2] + col] + wAr[r][3] * G[iAo[r][3] + col];
          bias_c[n][r] = s;
        }
      }
    }
    // ---- QK^T (3-pass hi/lo), A from registers ----
    #pragma unroll
    for (int ks = 0; ks < 2; ++ks) {
      int cslot = ((ks * 4 + lq) ^ (l16 & 7)) * 8;
      #pragma unroll
      for (int n = 0; n < 4; ++n) {
        int brow = (n * 16 + l16) * 64;
        bf16x8 bH = *(const bf16x8*)&sKh[cur][brow + cslot];
        bf16x8 bL = *(const bf16x8*)&sKl[cur][brow + cslot];
        sacc[n] = MFMA16(qh[ks], bH, sacc[n]);
        sacc[n] = MFMA16(qh[ks], bL, sacc[n]);
        sacc[n] = MFMA16(ql[ks], bH, sacc[n]);
      }
    }
    // ---- online softmax (C-layout rows), P -> per-wave LDS tile ----
    #pragma unroll
    for (int r = 0; r < 4; ++r) {
      float mt = fmaxf(fmaxf(sacc[0][r], sacc[1][r]), fmaxf(sacc[2][r], sacc[3][r]));
      #pragma unroll
      for (int msk = 1; msk < 16; msk <<= 1) mt = fmaxf(mt, __shfl_xor(mt, msk));
      float mn = fmaxf(mrow[r], mt);
      float sc = __expf(mrow[r] - mn);
      float ts = 0.f;
      #pragma unroll
      for (int n = 0; n < 4; ++n) {
        float p = __expf(sacc[n][r] - mn);
        ts += p;
        myP[(lq * 4 + r) * 72 + n * 16 + l16] = f2bf(p);
      }
      #pragma unroll
      for (int msk = 1; msk < 16; msk <<= 1) ts += __shfl_xor(ts, msk);
      lrow[r] = lrow[r] * sc + ts;
      mrow[r] = mn;
      #pragma unroll
      for (int n = 0; n < 4; ++n) oacc[n][r] *= sc;
    }
    // ---- PV: A = P [16q][64k] (per-wave), B = V^T [16d][64k] ----
    #pragma unroll
    for (int ks = 0; ks < 2; ++ks) {
      bf16x8 pa = *(const bf16x8*)&myP[l16 * 72 + (ks * 4 + lq) * 8];
      int cslot = ((ks * 4 + lq) ^ (l16 & 7)) * 8;
      #pragma unroll
      for (int n = 0; n < 4; ++n) {
        bf16x8 bv = *(const bf16x8*)&sVt[cur][(n * 16 + l16) * 64 + cslot];
        oacc[n] = MFMA16(pa, bv, oacc[n]);
      }
    }
    __syncthreads();  // drains stage(jt+1); all waves done reading buf cur
    cur ^= 1;
  }
  // ---- epilogue ----
  #pragma unroll
  for (int r = 0; r < 4; ++r) {
    float inv = 1.0f / lrow[r];
    int qr = i0 + w * 16 + lq * 4 + r;
    #pragma unroll
    for (int n = 0; n < 4; ++n) {
      float v = oacc[n][r] * inv;
      ushort hb = f2bf(v);
      size_t o = ((size_t)b * 1024 + qr) * 512 + h * 64 + n * 16 + l16;
      Oh[o] = hb;
      Ol[o] = f2bf(v - bf2f(hb));
    }
  }
}

// ---------------------------------------------------------------------------
extern "C" void kernel_launch(void* const* d_in, const int* in_sizes, int n_in,
                              void* d_out, int out_size, void* d_ws, size_t ws_size,
                              hipStream_t stream) {
  const float* x     = (const float*)d_in[0];
  const float* q_w   = (const float*)d_in[1];
  const float* q_b   = (const float*)d_in[2];
  const float* k_w   = (const float*)d_in[3];
  const float* k_b   = (const float*)d_in[4];
  const float* v_w   = (const float*)d_in[5];
  const float* v_b   = (const float*)d_in[6];
  const float* o_w   = (const float*)d_in[7];
  const float* o_b   = (const float*)d_in[8];
  const float* dw_w  = (const float*)d_in[9];
  const float* dw_b  = (const float*)d_in[10];
  const float* off_w = (const float*)d_in[11];
  const float* btab  = (const float*)d_in[12];

  float* ws = (float*)d_ws;
  const size_t SZ = (size_t)4 * 1024 * 512;  // 2M elements
  float* Q    = ws;
  float* K    = ws + SZ;
  float* V    = ws + 2 * SZ;
  float* G    = ws + 3 * SZ;                 // 64K floats
  float* samp = ws + 3 * SZ + 65536;         // 65536 floats

  ushort* u = (ushort*)(samp + 65536);
  ushort* Xhi  = u;                          // 2M each
  ushort* Xlo  = Xhi + SZ;
  ushort* Wq_h = Xlo + SZ;                   // 256K each, 8 buffers
  ushort* Wq_l = Wq_h + 262144;
  ushort* Wk_h = Wq_h + 2 * 262144;
  ushort* Wk_l = Wq_h + 3 * 262144;
  ushort* Wv_h = Wq_h + 4 * 262144;
  ushort* Wv_l = Wq_h + 5 * 262144;
  ushort* Wo_h = Wq_h + 6 * 262144;
  ushort* Wo_l = Wq_h + 7 * 262144;
  ushort* Ksh  = Wq_h + 8 * 262144;          // 2M each
  ushort* Ksl  = Ksh + SZ;
  ushort* Vtr  = Ksl + SZ;
  ushort* Aoh  = Vtr + SZ;
  ushort* Aol  = Aoh + SZ;
  float* dwT   = (float*)(Aol + SZ);         // 25*512 floats

  split_kernel<<<2048, 256, 0, stream>>>(x, Xhi, Xlo, 524288);
  prep_weights<<<1026, 256, 0, stream>>>(q_w, k_w, v_w, o_w, dw_w, Wq_h, Wq_l,
                                         Wk_h, Wk_l, Wv_h, Wv_l, Wo_h, Wo_l, dwT);

  gemm_qkv<<<dim3(24, 32), 256, 0, stream>>>(Xhi, Xlo, Wq_h, Wq_l, Wk_h, Wk_l,
                                             Wv_h, Wv_l, q_b, k_b, v_b, Q, K, V);

  offset_net2<<<dim3(2, 32, 4), 256, 0, stream>>>(x, dwT, dw_b, off_w, samp);
  g_kernel<<<64, 256, 0, stream>>>(btab, G);
  grid_sample<<<dim3(16, 32), 256, 0, stream>>>(K, V, samp, Ksh, Ksl, Vtr);

  attn_mfma<<<512, 256, 0, stream>>>(Q, Ksh, Ksl, Vtr, G, Aoh, Aol);

  gemm_mfma<<<dim3(8, 32), 256, 0, stream>>>(Aoh, Aol, Wo_h, Wo_l, o_b,
                                             (float*)d_out);
}

// Round 7
// 148.220 us; speedup vs baseline: 1.0996x; 1.0996x over previous
//
#include <hip/hip_runtime.h>
#include <math.h>

typedef unsigned short ushort;
typedef __attribute__((ext_vector_type(8))) short bf16x8;
typedef __attribute__((ext_vector_type(4))) float f32x4;

#define MFMA16(a, b, c) __builtin_amdgcn_mfma_f32_16x16x32_bf16(a, b, c, 0, 0, 0)
#define GLOAD16(g, l)                                                   \
  __builtin_amdgcn_global_load_lds(                                     \
      (const __attribute__((address_space(1))) unsigned int*)(g),       \
      (__attribute__((address_space(3))) unsigned int*)(l), 16, 0, 0)

__device__ __forceinline__ ushort f2bf(float f) {
  unsigned u = __float_as_uint(f);
  u += 0x7FFFu + ((u >> 16) & 1u);  // RNE
  return (ushort)(u >> 16);
}
__device__ __forceinline__ float bf2f(ushort b) {
  return __uint_as_float(((unsigned)b) << 16);
}
// packed bf16 pair: low = bf16(a), high = bf16(b)
__device__ __forceinline__ unsigned pk_bf16(float a, float b) {
  unsigned u;
  asm("v_cvt_pk_bf16_f32 %0, %1, %2" : "=v"(u) : "v"(a), "v"(b));
  return u;
}

// ---------------------------------------------------------------------------
// Split fp32 -> (hi, lo) bf16 pair.  n4 = element_count/4.
// ---------------------------------------------------------------------------
__global__ __launch_bounds__(256) void split_kernel(
    const float* __restrict__ in, ushort* __restrict__ hi,
    ushort* __restrict__ lo, int n4) {
  int i = blockIdx.x * 256 + threadIdx.x;
  if (i >= n4) return;
  float4 v = ((const float4*)in)[i];
  ushort4 h, l;
  h.x = f2bf(v.x); l.x = f2bf(v.x - bf2f(h.x));
  h.y = f2bf(v.y); l.y = f2bf(v.y - bf2f(h.y));
  h.z = f2bf(v.z); l.z = f2bf(v.z - bf2f(h.z));
  h.w = f2bf(v.w); l.w = f2bf(v.w - bf2f(h.w));
  ((ushort4*)hi)[i] = h;
  ((ushort4*)lo)[i] = l;
}

// ---------------------------------------------------------------------------
// Fused weight prep: 4 weight splits (hi/lo bf16) + dw transpose, one launch.
// ---------------------------------------------------------------------------
__global__ __launch_bounds__(256) void prep_weights(
    const float* __restrict__ q_w, const float* __restrict__ k_w,
    const float* __restrict__ v_w, const float* __restrict__ o_w,
    const float* __restrict__ dw_w, ushort* __restrict__ Wqh,
    ushort* __restrict__ Wql, ushort* __restrict__ Wkh,
    ushort* __restrict__ Wkl, ushort* __restrict__ Wvh,
    ushort* __restrict__ Wvl, ushort* __restrict__ Woh,
    ushort* __restrict__ Wol, float* __restrict__ dwT) {
  int blk = blockIdx.x;
  if (blk < 1024) {
    int grp = blk >> 8;
    const float* in = grp == 0 ? q_w : grp == 1 ? k_w : grp == 2 ? v_w : o_w;
    ushort* hi = grp == 0 ? Wqh : grp == 1 ? Wkh : grp == 2 ? Wvh : Woh;
    ushort* lo = grp == 0 ? Wql : grp == 1 ? Wkl : grp == 2 ? Wvl : Wol;
    int i = (blk & 255) * 256 + threadIdx.x;
    float4 v = ((const float4*)in)[i];
    ushort4 h, l;
    h.x = f2bf(v.x); l.x = f2bf(v.x - bf2f(h.x));
    h.y = f2bf(v.y); l.y = f2bf(v.y - bf2f(h.y));
    h.z = f2bf(v.z); l.z = f2bf(v.z - bf2f(h.z));
    h.w = f2bf(v.w); l.w = f2bf(v.w - bf2f(h.w));
    ((ushort4*)hi)[i] = h;
    ((ushort4*)lo)[i] = l;
  } else {
    int c = (blk - 1024) * 256 + threadIdx.x;
    #pragma unroll
    for (int k = 0; k < 25; ++k) dwT[k * 512 + c] = dw_w[c * 25 + k];
  }
}

// ---------------------------------------------------------------------------
// MFMA GEMM body: Y[.,512]=A@W^T+b, hi/lo 3-pass.
// ---------------------------------------------------------------------------
__device__ __forceinline__ void gemm_body(
    const ushort* __restrict__ Ahi, const ushort* __restrict__ Alo,
    const ushort* __restrict__ Bhi, const ushort* __restrict__ Blo,
    const float* __restrict__ bias, float* __restrict__ Y,
    int m0, int n0, ushort* lds) {
  ushort* sAhi = lds;
  ushort* sAlo = lds + 8192;
  ushort* sBhi = lds + 16384;
  ushort* sBlo = lds + 20480;
  int tid = threadIdx.x;
  int lane = tid & 63;
  int w = tid >> 6;
  int wr = (w >> 1) * 64;
  int wc = (w & 1) * 32;
  int l8r = lane >> 3;
  int sll = ((lane & 7) ^ l8r) << 3;
  int l16 = lane & 15, lq = lane >> 4;

  f32x4 acc[4][2];
  f32x4 zero = {0.f, 0.f, 0.f, 0.f};
  #pragma unroll
  for (int m = 0; m < 4; ++m)
    #pragma unroll
    for (int n = 0; n < 2; ++n) acc[m][n] = zero;

  for (int kt = 0; kt < 8; ++kt) {
    int kk = kt * 64;
    __syncthreads();
    #pragma unroll
    for (int q = 0; q < 4; ++q) {
      int ci = w * 4 + q;
      size_t go = (size_t)(m0 + ci * 8 + l8r) * 512 + kk + sll;
      GLOAD16(Ahi + go, sAhi + ci * 512);
      GLOAD16(Alo + go, sAlo + ci * 512);
    }
    #pragma unroll
    for (int q = 0; q < 2; ++q) {
      int ci = w * 2 + q;
      size_t go = (size_t)(n0 + ci * 8 + l8r) * 512 + kk + sll;
      GLOAD16(Bhi + go, sBhi + ci * 512);
      GLOAD16(Blo + go, sBlo + ci * 512);
    }
    __syncthreads();
    #pragma unroll
    for (int ks = 0; ks < 2; ++ks) {
      int slot = ks * 4 + lq;
      bf16x8 ah[4], al[4], bh[2], bl[2];
      #pragma unroll
      for (int m = 0; m < 4; ++m) {
        int r = wr + m * 16 + l16;
        int ph = (slot ^ (r & 7)) << 3;
        ah[m] = *(const bf16x8*)&sAhi[r * 64 + ph];
        al[m] = *(const bf16x8*)&sAlo[r * 64 + ph];
      }
      #pragma unroll
      for (int n = 0; n < 2; ++n) {
        int r = wc + n * 16 + l16;
        int ph = (slot ^ (r & 7)) << 3;
        bh[n] = *(const bf16x8*)&sBhi[r * 64 + ph];
        bl[n] = *(const bf16x8*)&sBlo[r * 64 + ph];
      }
      #pragma unroll
      for (int m = 0; m < 4; ++m)
        #pragma unroll
        for (int n = 0; n < 2; ++n) {
          acc[m][n] = MFMA16(ah[m], bh[n], acc[m][n]);
          acc[m][n] = MFMA16(ah[m], bl[n], acc[m][n]);
          acc[m][n] = MFMA16(al[m], bh[n], acc[m][n]);
        }
    }
  }
  #pragma unroll
  for (int n = 0; n < 2; ++n) {
    int col = n0 + wc + n * 16 + l16;
    float bv = bias[col];
    #pragma unroll
    for (int m = 0; m < 4; ++m) {
      #pragma unroll
      for (int j = 0; j < 4; ++j) {
        int row = m0 + wr + m * 16 + lq * 4 + j;
        Y[(size_t)row * 512 + col] = acc[m][n][j] + bv;
      }
    }
  }
}

__global__ __launch_bounds__(256) void gemm_qkv(
    const ushort* __restrict__ Ahi, const ushort* __restrict__ Alo,
    const ushort* __restrict__ Wh0, const ushort* __restrict__ Wl0,
    const ushort* __restrict__ Wh1, const ushort* __restrict__ Wl1,
    const ushort* __restrict__ Wh2, const ushort* __restrict__ Wl2,
    const float* __restrict__ b0, const float* __restrict__ b1,
    const float* __restrict__ b2, float* __restrict__ Y0,
    float* __restrict__ Y1, float* __restrict__ Y2) {
  __shared__ ushort lds[24576];
  int which = blockIdx.x >> 3;
  int n0 = (blockIdx.x & 7) * 64;
  int m0 = blockIdx.y * 128;
  const ushort* Bh; const ushort* Bl; const float* bb; float* Y;
  if (which == 0)      { Bh = Wh0; Bl = Wl0; bb = b0; Y = Y0; }
  else if (which == 1) { Bh = Wh1; Bl = Wl1; bb = b1; Y = Y1; }
  else                 { Bh = Wh2; Bl = Wl2; bb = b2; Y = Y2; }
  gemm_body(Ahi, Alo, Bh, Bl, bb, Y, m0, n0, lds);
}

__global__ __launch_bounds__(256) void gemm_mfma(
    const ushort* __restrict__ Ahi, const ushort* __restrict__ Alo,
    const ushort* __restrict__ Bhi, const ushort* __restrict__ Blo,
    const float* __restrict__ bias, float* __restrict__ Y) {
  __shared__ ushort lds[24576];
  gemm_body(Ahi, Alo, Bhi, Blo, bias, Y, blockIdx.y * 128, blockIdx.x * 64, lds);
}

// ---------------------------------------------------------------------------
// Offset network v2 (register sliding-window depthwise conv).
// ---------------------------------------------------------------------------
__global__ __launch_bounds__(256) void offset_net2(
    const float* __restrict__ x, const float* __restrict__ dwT,
    const float* __restrict__ dw_b, const float* __restrict__ off_w,
    float* __restrict__ samp) {
  __shared__ float wT[16][516];
  __shared__ float hT[16][516];
  __shared__ float ofs[16][16];
  int x0 = blockIdx.x * 16;
  int y = blockIdx.y;
  int b = blockIdx.z;
  int tid = threadIdx.x;

  for (int e = tid; e < 2048; e += 256) {
    int o = e >> 7, c4 = e & 127;
    *(float4*)&wT[o][c4 * 4] = *(const float4*)&off_w[o * 512 + c4 * 4];
  }

  int c = tid * 2;
  float2 dwv[25];
  #pragma unroll
  for (int k = 0; k < 25; ++k) dwv[k] = *(const float2*)&dwT[k * 512 + c];
  float2 cb = *(const float2*)&dw_b[c];

  const float* xb = x + (size_t)b * 1024 * 512 + c;
  bool rv[5];
  #pragma unroll
  for (int r = 0; r < 5; ++r) {
    int yy = y - 2 + r;
    rv[r] = (yy >= 0 && yy < 32);
  }
  float2 win[5][5];
  #pragma unroll
  for (int j = 0; j < 4; ++j) {
    int xc = x0 - 2 + j;
    bool cvld = (xc >= 0 && xc < 32);
    #pragma unroll
    for (int r = 0; r < 5; ++r) {
      win[r][j] = (rv[r] && cvld)
          ? *(const float2*)&xb[(size_t)((y - 2 + r) * 32 + xc) * 512]
          : make_float2(0.f, 0.f);
    }
  }
  #pragma unroll
  for (int i = 0; i < 16; ++i) {
    int xc = x0 + i + 2;
    bool cvld = (xc < 32);
    #pragma unroll
    for (int r = 0; r < 5; ++r) {
      win[r][4] = (rv[r] && cvld)
          ? *(const float2*)&xb[(size_t)((y - 2 + r) * 32 + xc) * 512]
          : make_float2(0.f, 0.f);
    }
    float sx = cb.x, sy = cb.y;
    #pragma unroll
    for (int r = 0; r < 5; ++r)
      #pragma unroll
      for (int j = 0; j < 5; ++j) {
        sx += win[r][j].x * dwv[r * 5 + j].x;
        sy += win[r][j].y * dwv[r * 5 + j].y;
      }
    float g0 = 0.5f * sx * (1.0f + erff(sx * 0.70710678118654752f));
    float g1 = 0.5f * sy * (1.0f + erff(sy * 0.70710678118654752f));
    *(float2*)&hT[i][c] = make_float2(g0, g1);
    #pragma unroll
    for (int r = 0; r < 5; ++r) {
      win[r][0] = win[r][1]; win[r][1] = win[r][2];
      win[r][2] = win[r][3]; win[r][3] = win[r][4];
    }
  }
  __syncthreads();

  {
    int o = tid & 15, px = tid >> 4;
    float acc = 0.f;
    #pragma unroll 4
    for (int c4 = 0; c4 < 128; ++c4) {
      float4 hv = *(const float4*)&hT[px][c4 * 4];
      float4 wv = *(const float4*)&wT[o][c4 * 4];
      acc += hv.x * wv.x + hv.y * wv.y + hv.z * wv.z + hv.w * wv.w;
    }
    ofs[px][o] = tanhf(acc) * 2.0f;
  }
  __syncthreads();

  if (tid < 128) {
    int px = tid >> 3, h = tid & 7;
    int n = y * 32 + x0 + px;
    float gx = -1.0f + 2.0f * (float)(x0 + px) / 31.0f;
    float gy = -1.0f + 2.0f * (float)y / 31.0f;
    float sx = fminf(fmaxf(gx + ofs[px][2 * h], -1.0f), 1.0f);
    float sy = fminf(fmaxf(gy + ofs[px][2 * h + 1], -1.0f), 1.0f);
    float2 pc;
    pc.x = (sx + 1.0f) * 16.0f - 0.5f;
    pc.y = (sy + 1.0f) * 16.0f - 0.5f;
    ((float2*)samp)[(size_t)(b * 8 + h) * 1024 + n] = pc;
  }
}

// ---------------------------------------------------------------------------
// Bilinear grid-sample of K and V -> Ks hi/lo [bh][1024][64], Vt [bh][64][1024]
// ---------------------------------------------------------------------------
__global__ __launch_bounds__(256) void grid_sample(
    const float* __restrict__ K, const float* __restrict__ V,
    const float* __restrict__ samp, ushort* __restrict__ Ksh,
    ushort* __restrict__ Ksl, ushort* __restrict__ Vt) {
  __shared__ ushort sV[64][72];
  int bh = blockIdx.y;
  int b = bh >> 3, h = bh & 7;
  int jb = blockIdx.x;
  int d = threadIdx.x & 63;
  for (int p = 0; p < 16; ++p) {
    int jl = p * 4 + (threadIdx.x >> 6);
    int j = jb * 64 + jl;
    float2 pc = ((const float2*)samp)[(size_t)bh * 1024 + j];
    float gx = pc.x, gy = pc.y;
    float x0 = floorf(gx), y0 = floorf(gy);
    float aK = 0.f, aV = 0.f;
    #pragma unroll
    for (int dy = 0; dy < 2; ++dy)
      #pragma unroll
      for (int dx = 0; dx < 2; ++dx) {
        float xi = x0 + (float)dx, yi = y0 + (float)dy;
        float wgt = (1.0f - fabsf(gx - xi)) * (1.0f - fabsf(gy - yi));
        if (xi >= 0.f && xi < 32.f && yi >= 0.f && yi < 32.f) {
          size_t base = ((size_t)b * 1024 + (int)yi * 32 + (int)xi) * 512 + h * 64 + d;
          aK += K[base] * wgt;
          aV += V[base] * wgt;
        }
      }
    ushort kh = f2bf(aK);
    size_t o = ((size_t)bh * 1024 + j) * 64 + d;
    Ksh[o] = kh;
    Ksl[o] = f2bf(aK - bf2f(kh));
    sV[jl][d] = f2bf(aV);
  }
  __syncthreads();
  int dd = threadIdx.x >> 2, c4 = threadIdx.x & 3;
  bf16x8 v0, v1;
  #pragma unroll
  for (int k = 0; k < 8; ++k) v0[k] = (short)sV[c4 * 16 + k][dd];
  #pragma unroll
  for (int k = 0; k < 8; ++k) v1[k] = (short)sV[c4 * 16 + 8 + k][dd];
  size_t o = ((size_t)bh * 64 + dd) * 1024 + jb * 64 + c4 * 16;
  *(bf16x8*)&Vt[o] = v0;
  *(bf16x8*)&Vt[o + 8] = v1;
}

// ---------------------------------------------------------------------------
// Bicubic taps + dense relative-position bias [1024][1024] (4 MB).
// ---------------------------------------------------------------------------
__device__ __forceinline__ void bicubic_taps(int i, float* w, int* idx) {
  const float a = -0.75f;
  float src = ((float)i + 0.5f) * 0.0625f - 0.5f;
  float fi = floorf(src);
  int i0 = (int)fi;
  float t = src - fi;
  #pragma unroll
  for (int k = -1; k <= 2; ++k) {
    float d = fabsf(t - (float)k);
    float wv;
    if (d <= 1.0f)
      wv = ((a + 2.0f) * d - (a + 3.0f)) * d * d + 1.0f;
    else if (d < 2.0f)
      wv = a * (((d - 5.0f) * d + 8.0f) * d - 4.0f);
    else
      wv = 0.0f;
    int ic = i0 + k;
    ic = ic < 0 ? 0 : (ic > 63 ? 63 : ic);
    w[k + 1] = wv;
    idx[k + 1] = ic;
  }
}

__global__ __launch_bounds__(256) void bias_kernel(
    const float* __restrict__ table, float* __restrict__ bias) {
  __shared__ float tab[225];
  int i = blockIdx.x;
  int tid = threadIdx.x;
  if (tid < 225) tab[tid] = table[tid];
  __syncthreads();
  float wA[4]; int iA[4];
  bicubic_taps(i, wA, iA);
  for (int j = tid; j < 1024; j += 256) {
    float wB[4]; int iB[4];
    bicubic_taps(j, wB, iB);
    float sum = 0.f;
    #pragma unroll
    for (int ka = 0; ka < 4; ++ka) {
      int pa = iA[ka];
      int py = pa >> 3, px = pa & 7;
      float wa = wA[ka];
      #pragma unroll
      for (int kb = 0; kb < 4; ++kb) {
        int qb = iB[kb];
        int qy = qb >> 3, qx = qb & 7;
        sum += wa * wB[kb] * tab[(py - qy + 7) * 15 + (px - qx + 7)];
      }
    }
    bias[(size_t)i * 1024 + j] = sum;
  }
}

// ---------------------------------------------------------------------------
// MFMA flash attention v4: SWAPPED QK^T (S^T = K x Q) so each lane owns one
// query's scores -> softmax reduce is 15 in-reg fmax + 2 shfl (was 32 shfl).
// Dense bias loaded as 4x float4 per tile (contiguous in key). XCD-swizzled
// grid, Q in registers, K/V LDS double-buffered, one barrier per KV-tile.
// ---------------------------------------------------------------------------
__global__ __launch_bounds__(256) void attn_mfma(
    const float* __restrict__ Q, const ushort* __restrict__ Kh,
    const ushort* __restrict__ Kl, const ushort* __restrict__ Vt,
    const float* __restrict__ bias, ushort* __restrict__ Oh,
    ushort* __restrict__ Ol) {
  __shared__ ushort sKh[2][4096];
  __shared__ ushort sKl[2][4096];
  __shared__ ushort sVt[2][4096];
  __shared__ ushort sP[4][1216];  // per-wave [16 q][76] (pitch 76 -> 16 banks)

  int tid = threadIdx.x;
  int lane = tid & 63;
  int w = tid >> 6;
  int l16 = lane & 15, lq = lane >> 4;
  int blk = blockIdx.x;
  int xcd = blk & 7;
  int rr = blk >> 3;
  int bh = ((rr & 3) << 3) + xcd;
  int i0 = (rr >> 2) * 64;
  int b = bh >> 3, h = bh & 7;
  int r8 = lane >> 3, ch = lane & 7;

  // Q fragments (this wave's 16 rows), *0.125, hi/lo
  bf16x8 qh[2], ql[2];
  #pragma unroll
  for (int s = 0; s < 2; ++s) {
    const float* qp =
        Q + ((size_t)b * 1024 + i0 + w * 16 + l16) * 512 + h * 64 + s * 32 + lq * 8;
    #pragma unroll
    for (int j = 0; j < 8; ++j) {
      float f = qp[j] * 0.125f;
      ushort hb = f2bf(f);
      qh[s][j] = (short)hb;
      ql[s][j] = (short)f2bf(f - bf2f(hb));
    }
  }

  f32x4 oacc[4];
  f32x4 zero = {0.f, 0.f, 0.f, 0.f};
  #pragma unroll
  for (int n = 0; n < 4; ++n) oacc[n] = zero;
  float mq = -INFINITY, lsum = 0.f;  // per-query (l16) online-softmax state

  ushort* myP = sP[w];
  int stgrow0 = w * 16;
  int grow0 = stgrow0 + r8;
  const float* bprow = bias + (size_t)(i0 + w * 16 + l16) * 1024;

  // ---- prologue: stage tile 0; preload bias(0) (swapped: contiguous keys) ----
  #pragma unroll
  for (int q = 0; q < 2; ++q) {
    int row = grow0 + q * 8;
    int gch = ch ^ (row & 7);
    size_t gk = ((size_t)bh * 1024 + row) * 64 + gch * 8;
    GLOAD16(Kh + gk, &sKh[0][(stgrow0 + q * 8) * 64]);
    GLOAD16(Kl + gk, &sKl[0][(stgrow0 + q * 8) * 64]);
    size_t gv = ((size_t)bh * 64 + row) * 1024 + gch * 8;
    GLOAD16(Vt + gv, &sVt[0][(stgrow0 + q * 8) * 64]);
  }
  f32x4 bias_c[4];
  #pragma unroll
  for (int n = 0; n < 4; ++n)
    bias_c[n] = *(const f32x4*)&bprow[n * 16 + lq * 4];
  __syncthreads();

  int cur = 0;
  for (int jt = 0; jt < 16; ++jt) {
    // ---- issue stage of tile jt+1 ----
    if (jt < 15) {
      #pragma unroll
      for (int q = 0; q < 2; ++q) {
        int row = grow0 + q * 8;
        int gch = ch ^ (row & 7);
        size_t gk = ((size_t)bh * 1024 + (jt + 1) * 64 + row) * 64 + gch * 8;
        GLOAD16(Kh + gk, &sKh[cur ^ 1][(stgrow0 + q * 8) * 64]);
        GLOAD16(Kl + gk, &sKl[cur ^ 1][(stgrow0 + q * 8) * 64]);
        size_t gv = ((size_t)bh * 64 + row) * 1024 + (jt + 1) * 64 + gch * 8;
        GLOAD16(Vt + gv, &sVt[cur ^ 1][(stgrow0 + q * 8) * 64]);
      }
    }
    // sacc init = bias^T tile; prefetch next tile's bias
    f32x4 sacc[4];
    #pragma unroll
    for (int n = 0; n < 4; ++n) sacc[n] = bias_c[n];
    if (jt < 15) {
      #pragma unroll
      for (int n = 0; n < 4; ++n)
        bias_c[n] = *(const f32x4*)&bprow[(jt + 1) * 64 + n * 16 + lq * 4];
    }
    // ---- SWAPPED QK^T: A = K (LDS), B = Q (regs) -> S^T[key][query] ----
    #pragma unroll
    for (int ks = 0; ks < 2; ++ks) {
      int cslot = ((ks * 4 + lq) ^ (l16 & 7)) * 8;
      #pragma unroll
      for (int n = 0; n < 4; ++n) {
        int brow = (n * 16 + l16) * 64;
        bf16x8 aH = *(const bf16x8*)&sKh[cur][brow + cslot];
        bf16x8 aL = *(const bf16x8*)&sKl[cur][brow + cslot];
        sacc[n] = MFMA16(aH, qh[ks], sacc[n]);
        sacc[n] = MFMA16(aL, qh[ks], sacc[n]);
        sacc[n] = MFMA16(aH, ql[ks], sacc[n]);
      }
    }
    // ---- softmax: lane holds 16 scores of query l16 over keys ----
    float mt = sacc[0][0];
    #pragma unroll
    for (int n = 0; n < 4; ++n)
      #pragma unroll
      for (int r = 0; r < 4; ++r) mt = fmaxf(mt, sacc[n][r]);
    mt = fmaxf(mt, __shfl_xor(mt, 16));
    mt = fmaxf(mt, __shfl_xor(mt, 32));
    float mn = fmaxf(mq, mt);
    float sc = __expf(mq - mn);
    float ts = 0.f;
    unsigned pkv[4][2];
    #pragma unroll
    for (int n = 0; n < 4; ++n) {
      float p0 = __expf(sacc[n][0] - mn);
      float p1 = __expf(sacc[n][1] - mn);
      float p2 = __expf(sacc[n][2] - mn);
      float p3 = __expf(sacc[n][3] - mn);
      ts += (p0 + p1) + (p2 + p3);
      pkv[n][0] = pk_bf16(p0, p1);
      pkv[n][1] = pk_bf16(p2, p3);
    }
    ts += __shfl_xor(ts, 16);
    ts += __shfl_xor(ts, 32);
    lsum = lsum * sc + ts;
    mq = mn;
    // rescale O rows: factor of query lq*4+r lives in lane lq*4+r
    float scq[4];
    #pragma unroll
    for (int r = 0; r < 4; ++r) scq[r] = __shfl(sc, lq * 4 + r);
    #pragma unroll
    for (int n = 0; n < 4; ++n)
      #pragma unroll
      for (int r = 0; r < 4; ++r) oacc[n][r] *= scq[r];
    // write P[q=l16][keys] : 4x ds_write_b64, pitch 76 ushorts
    #pragma unroll
    for (int n = 0; n < 4; ++n) {
      uint2 u = make_uint2(pkv[n][0], pkv[n][1]);
      *(uint2*)&myP[l16 * 76 + n * 16 + lq * 4] = u;
    }
    // ---- PV: A = P [16q][64k] (per-wave), B = V^T [16d][64k] ----
    #pragma unroll
    for (int ks = 0; ks < 2; ++ks) {
      bf16x8 pa = *(const bf16x8*)&myP[l16 * 76 + ks * 32 + lq * 8];
      int cslot = ((ks * 4 + lq) ^ (l16 & 7)) * 8;
      #pragma unroll
      for (int n = 0; n < 4; ++n) {
        bf16x8 bv = *(const bf16x8*)&sVt[cur][(n * 16 + l16) * 64 + cslot];
        oacc[n] = MFMA16(pa, bv, oacc[n]);
      }
    }
    __syncthreads();  // drains stage(jt+1); all waves done with buf cur
    cur ^= 1;
  }
  // ---- epilogue: per-query 1/l, transposed to oacc layout ----
  float linv = 1.0f / lsum;
  float invq[4];
  #pragma unroll
  for (int r = 0; r < 4; ++r) invq[r] = __shfl(linv, lq * 4 + r);
  #pragma unroll
  for (int r = 0; r < 4; ++r) {
    int qr = i0 + w * 16 + lq * 4 + r;
    #pragma unroll
    for (int n = 0; n < 4; ++n) {
      float v = oacc[n][r] * invq[r];
      ushort hb = f2bf(v);
      size_t o = ((size_t)b * 1024 + qr) * 512 + h * 64 + n * 16 + l16;
      Oh[o] = hb;
      Ol[o] = f2bf(v - bf2f(hb));
    }
  }
}

// ---------------------------------------------------------------------------
extern "C" void kernel_launch(void* const* d_in, const int* in_sizes, int n_in,
                              void* d_out, int out_size, void* d_ws, size_t ws_size,
                              hipStream_t stream) {
  const float* x     = (const float*)d_in[0];
  const float* q_w   = (const float*)d_in[1];
  const float* q_b   = (const float*)d_in[2];
  const float* k_w   = (const float*)d_in[3];
  const float* k_b   = (const float*)d_in[4];
  const float* v_w   = (const float*)d_in[5];
  const float* v_b   = (const float*)d_in[6];
  const float* o_w   = (const float*)d_in[7];
  const float* o_b   = (const float*)d_in[8];
  const float* dw_w  = (const float*)d_in[9];
  const float* dw_b  = (const float*)d_in[10];
  const float* off_w = (const float*)d_in[11];
  const float* btab  = (const float*)d_in[12];

  float* ws = (float*)d_ws;
  const size_t SZ = (size_t)4 * 1024 * 512;  // 2M elements
  float* Q    = ws;
  float* K    = ws + SZ;
  float* V    = ws + 2 * SZ;
  float* bias = ws + 3 * SZ;                 // 1M floats (4 MB)
  float* samp = ws + 3 * SZ + 1048576;       // 65536 floats

  ushort* u = (ushort*)(samp + 65536);
  ushort* Xhi  = u;                          // 2M each
  ushort* Xlo  = Xhi + SZ;
  ushort* Wq_h = Xlo + SZ;                   // 256K each, 8 buffers
  ushort* Wq_l = Wq_h + 262144;
  ushort* Wk_h = Wq_h + 2 * 262144;
  ushort* Wk_l = Wq_h + 3 * 262144;
  ushort* Wv_h = Wq_h + 4 * 262144;
  ushort* Wv_l = Wq_h + 5 * 262144;
  ushort* Wo_h = Wq_h + 6 * 262144;
  ushort* Wo_l = Wq_h + 7 * 262144;
  ushort* Ksh  = Wq_h + 8 * 262144;          // 2M each
  ushort* Ksl  = Ksh + SZ;
  ushort* Vtr  = Ksl + SZ;
  ushort* Aoh  = Vtr + SZ;
  ushort* Aol  = Aoh + SZ;
  float* dwT   = (float*)(Aol + SZ);         // 25*512 floats

  split_kernel<<<2048, 256, 0, stream>>>(x, Xhi, Xlo, 524288);
  prep_weights<<<1026, 256, 0, stream>>>(q_w, k_w, v_w, o_w, dw_w, Wq_h, Wq_l,
                                         Wk_h, Wk_l, Wv_h, Wv_l, Wo_h, Wo_l, dwT);

  gemm_qkv<<<dim3(24, 32), 256, 0, stream>>>(Xhi, Xlo, Wq_h, Wq_l, Wk_h, Wk_l,
                                             Wv_h, Wv_l, q_b, k_b, v_b, Q, K, V);

  offset_net2<<<dim3(2, 32, 4), 256, 0, stream>>>(x, dwT, dw_b, off_w, samp);
  bias_kernel<<<1024, 256, 0, stream>>>(btab, bias);
  grid_sample<<<dim3(16, 32), 256, 0, stream>>>(K, V, samp, Ksh, Ksl, Vtr);

  attn_mfma<<<512, 256, 0, stream>>>(Q, Ksh, Ksl, Vtr, bias, Aoh, Aol);

  gemm_mfma<<<dim3(8, 32), 256, 0, stream>>>(Aoh, Aol, Wo_h, Wo_l, o_b,
                                             (float*)d_out);
}

// Round 8
// 136.402 us; speedup vs baseline: 1.1949x; 1.0866x over previous
//
#include <hip/hip_runtime.h>
#include <math.h>

typedef unsigned short ushort;
typedef __attribute__((ext_vector_type(8))) short bf16x8;
typedef __attribute__((ext_vector_type(4))) float f32x4;

#define MFMA16(a, b, c) __builtin_amdgcn_mfma_f32_16x16x32_bf16(a, b, c, 0, 0, 0)
#define GLOAD16(g, l)                                                   \
  __builtin_amdgcn_global_load_lds(                                     \
      (const __attribute__((address_space(1))) unsigned int*)(g),       \
      (__attribute__((address_space(3))) unsigned int*)(l), 16, 0, 0)

__device__ __forceinline__ ushort f2bf(float f) {
  unsigned u = __float_as_uint(f);
  u += 0x7FFFu + ((u >> 16) & 1u);  // RNE
  return (ushort)(u >> 16);
}
__device__ __forceinline__ float bf2f(ushort b) {
  return __uint_as_float(((unsigned)b) << 16);
}
// packed bf16 pair: low = bf16(a), high = bf16(b)
__device__ __forceinline__ unsigned pk_bf16(float a, float b) {
  unsigned u;
  asm("v_cvt_pk_bf16_f32 %0, %1, %2" : "=v"(u) : "v"(a), "v"(b));
  return u;
}

// ---------------------------------------------------------------------------
// Split fp32 -> (hi, lo) bf16 pair.  n4 = element_count/4.
// ---------------------------------------------------------------------------
__global__ __launch_bounds__(256) void split_kernel(
    const float* __restrict__ in, ushort* __restrict__ hi,
    ushort* __restrict__ lo, int n4) {
  int i = blockIdx.x * 256 + threadIdx.x;
  if (i >= n4) return;
  float4 v = ((const float4*)in)[i];
  ushort4 h, l;
  h.x = f2bf(v.x); l.x = f2bf(v.x - bf2f(h.x));
  h.y = f2bf(v.y); l.y = f2bf(v.y - bf2f(h.y));
  h.z = f2bf(v.z); l.z = f2bf(v.z - bf2f(h.z));
  h.w = f2bf(v.w); l.w = f2bf(v.w - bf2f(h.w));
  ((ushort4*)hi)[i] = h;
  ((ushort4*)lo)[i] = l;
}

// ---------------------------------------------------------------------------
// Fused weight prep: 4 weight splits (hi/lo bf16) + dw transpose, one launch.
// ---------------------------------------------------------------------------
__global__ __launch_bounds__(256) void prep_weights(
    const float* __restrict__ q_w, const float* __restrict__ k_w,
    const float* __restrict__ v_w, const float* __restrict__ o_w,
    const float* __restrict__ dw_w, ushort* __restrict__ Wqh,
    ushort* __restrict__ Wql, ushort* __restrict__ Wkh,
    ushort* __restrict__ Wkl, ushort* __restrict__ Wvh,
    ushort* __restrict__ Wvl, ushort* __restrict__ Woh,
    ushort* __restrict__ Wol, float* __restrict__ dwT) {
  int blk = blockIdx.x;
  if (blk < 1024) {
    int grp = blk >> 8;
    const float* in = grp == 0 ? q_w : grp == 1 ? k_w : grp == 2 ? v_w : o_w;
    ushort* hi = grp == 0 ? Wqh : grp == 1 ? Wkh : grp == 2 ? Wvh : Woh;
    ushort* lo = grp == 0 ? Wql : grp == 1 ? Wkl : grp == 2 ? Wvl : Wol;
    int i = (blk & 255) * 256 + threadIdx.x;
    float4 v = ((const float4*)in)[i];
    ushort4 h, l;
    h.x = f2bf(v.x); l.x = f2bf(v.x - bf2f(h.x));
    h.y = f2bf(v.y); l.y = f2bf(v.y - bf2f(h.y));
    h.z = f2bf(v.z); l.z = f2bf(v.z - bf2f(h.z));
    h.w = f2bf(v.w); l.w = f2bf(v.w - bf2f(h.w));
    ((ushort4*)hi)[i] = h;
    ((ushort4*)lo)[i] = l;
  } else {
    int c = (blk - 1024) * 256 + threadIdx.x;
    #pragma unroll
    for (int k = 0; k < 25; ++k) dwT[k * 512 + c] = dw_w[c * 25 + k];
  }
}

// ---------------------------------------------------------------------------
// MFMA GEMM body: Y[.,512]=A@W^T+b, hi/lo 3-pass.
// ---------------------------------------------------------------------------
__device__ __forceinline__ void gemm_body(
    const ushort* __restrict__ Ahi, const ushort* __restrict__ Alo,
    const ushort* __restrict__ Bhi, const ushort* __restrict__ Blo,
    const float* __restrict__ bias, float* __restrict__ Y,
    int m0, int n0, ushort* lds) {
  ushort* sAhi = lds;
  ushort* sAlo = lds + 8192;
  ushort* sBhi = lds + 16384;
  ushort* sBlo = lds + 20480;
  int tid = threadIdx.x;
  int lane = tid & 63;
  int w = tid >> 6;
  int wr = (w >> 1) * 64;
  int wc = (w & 1) * 32;
  int l8r = lane >> 3;
  int sll = ((lane & 7) ^ l8r) << 3;
  int l16 = lane & 15, lq = lane >> 4;

  f32x4 acc[4][2];
  f32x4 zero = {0.f, 0.f, 0.f, 0.f};
  #pragma unroll
  for (int m = 0; m < 4; ++m)
    #pragma unroll
    for (int n = 0; n < 2; ++n) acc[m][n] = zero;

  for (int kt = 0; kt < 8; ++kt) {
    int kk = kt * 64;
    __syncthreads();
    #pragma unroll
    for (int q = 0; q < 4; ++q) {
      int ci = w * 4 + q;
      size_t go = (size_t)(m0 + ci * 8 + l8r) * 512 + kk + sll;
      GLOAD16(Ahi + go, sAhi + ci * 512);
      GLOAD16(Alo + go, sAlo + ci * 512);
    }
    #pragma unroll
    for (int q = 0; q < 2; ++q) {
      int ci = w * 2 + q;
      size_t go = (size_t)(n0 + ci * 8 + l8r) * 512 + kk + sll;
      GLOAD16(Bhi + go, sBhi + ci * 512);
      GLOAD16(Blo + go, sBlo + ci * 512);
    }
    __syncthreads();
    #pragma unroll
    for (int ks = 0; ks < 2; ++ks) {
      int slot = ks * 4 + lq;
      bf16x8 ah[4], al[4], bh[2], bl[2];
      #pragma unroll
      for (int m = 0; m < 4; ++m) {
        int r = wr + m * 16 + l16;
        int ph = (slot ^ (r & 7)) << 3;
        ah[m] = *(const bf16x8*)&sAhi[r * 64 + ph];
        al[m] = *(const bf16x8*)&sAlo[r * 64 + ph];
      }
      #pragma unroll
      for (int n = 0; n < 2; ++n) {
        int r = wc + n * 16 + l16;
        int ph = (slot ^ (r & 7)) << 3;
        bh[n] = *(const bf16x8*)&sBhi[r * 64 + ph];
        bl[n] = *(const bf16x8*)&sBlo[r * 64 + ph];
      }
      #pragma unroll
      for (int m = 0; m < 4; ++m)
        #pragma unroll
        for (int n = 0; n < 2; ++n) {
          acc[m][n] = MFMA16(ah[m], bh[n], acc[m][n]);
          acc[m][n] = MFMA16(ah[m], bl[n], acc[m][n]);
          acc[m][n] = MFMA16(al[m], bh[n], acc[m][n]);
        }
    }
  }
  #pragma unroll
  for (int n = 0; n < 2; ++n) {
    int col = n0 + wc + n * 16 + l16;
    float bv = bias[col];
    #pragma unroll
    for (int m = 0; m < 4; ++m) {
      #pragma unroll
      for (int j = 0; j < 4; ++j) {
        int row = m0 + wr + m * 16 + lq * 4 + j;
        Y[(size_t)row * 512 + col] = acc[m][n][j] + bv;
      }
    }
  }
}

__global__ __launch_bounds__(256) void gemm_qkv(
    const ushort* __restrict__ Ahi, const ushort* __restrict__ Alo,
    const ushort* __restrict__ Wh0, const ushort* __restrict__ Wl0,
    const ushort* __restrict__ Wh1, const ushort* __restrict__ Wl1,
    const ushort* __restrict__ Wh2, const ushort* __restrict__ Wl2,
    const float* __restrict__ b0, const float* __restrict__ b1,
    const float* __restrict__ b2, float* __restrict__ Y0,
    float* __restrict__ Y1, float* __restrict__ Y2) {
  __shared__ ushort lds[24576];
  int which = blockIdx.x >> 3;
  int n0 = (blockIdx.x & 7) * 64;
  int m0 = blockIdx.y * 128;
  const ushort* Bh; const ushort* Bl; const float* bb; float* Y;
  if (which == 0)      { Bh = Wh0; Bl = Wl0; bb = b0; Y = Y0; }
  else if (which == 1) { Bh = Wh1; Bl = Wl1; bb = b1; Y = Y1; }
  else                 { Bh = Wh2; Bl = Wl2; bb = b2; Y = Y2; }
  gemm_body(Ahi, Alo, Bh, Bl, bb, Y, m0, n0, lds);
}

__global__ __launch_bounds__(256) void gemm_mfma(
    const ushort* __restrict__ Ahi, const ushort* __restrict__ Alo,
    const ushort* __restrict__ Bhi, const ushort* __restrict__ Blo,
    const float* __restrict__ bias, float* __restrict__ Y) {
  __shared__ ushort lds[24576];
  gemm_body(Ahi, Alo, Bhi, Blo, bias, Y, blockIdx.y * 128, blockIdx.x * 64, lds);
}

// ---------------------------------------------------------------------------
// Offset network v2 (register sliding-window depthwise conv).
// ---------------------------------------------------------------------------
__global__ __launch_bounds__(256) void offset_net2(
    const float* __restrict__ x, const float* __restrict__ dwT,
    const float* __restrict__ dw_b, const float* __restrict__ off_w,
    float* __restrict__ samp) {
  __shared__ float wT[16][516];
  __shared__ float hT[16][516];
  __shared__ float ofs[16][16];
  int x0 = blockIdx.x * 16;
  int y = blockIdx.y;
  int b = blockIdx.z;
  int tid = threadIdx.x;

  for (int e = tid; e < 2048; e += 256) {
    int o = e >> 7, c4 = e & 127;
    *(float4*)&wT[o][c4 * 4] = *(const float4*)&off_w[o * 512 + c4 * 4];
  }

  int c = tid * 2;
  float2 dwv[25];
  #pragma unroll
  for (int k = 0; k < 25; ++k) dwv[k] = *(const float2*)&dwT[k * 512 + c];
  float2 cb = *(const float2*)&dw_b[c];

  const float* xb = x + (size_t)b * 1024 * 512 + c;
  bool rv[5];
  #pragma unroll
  for (int r = 0; r < 5; ++r) {
    int yy = y - 2 + r;
    rv[r] = (yy >= 0 && yy < 32);
  }
  float2 win[5][5];
  #pragma unroll
  for (int j = 0; j < 4; ++j) {
    int xc = x0 - 2 + j;
    bool cvld = (xc >= 0 && xc < 32);
    #pragma unroll
    for (int r = 0; r < 5; ++r) {
      win[r][j] = (rv[r] && cvld)
          ? *(const float2*)&xb[(size_t)((y - 2 + r) * 32 + xc) * 512]
          : make_float2(0.f, 0.f);
    }
  }
  #pragma unroll
  for (int i = 0; i < 16; ++i) {
    int xc = x0 + i + 2;
    bool cvld = (xc < 32);
    #pragma unroll
    for (int r = 0; r < 5; ++r) {
      win[r][4] = (rv[r] && cvld)
          ? *(const float2*)&xb[(size_t)((y - 2 + r) * 32 + xc) * 512]
          : make_float2(0.f, 0.f);
    }
    float sx = cb.x, sy = cb.y;
    #pragma unroll
    for (int r = 0; r < 5; ++r)
      #pragma unroll
      for (int j = 0; j < 5; ++j) {
        sx += win[r][j].x * dwv[r * 5 + j].x;
        sy += win[r][j].y * dwv[r * 5 + j].y;
      }
    float g0 = 0.5f * sx * (1.0f + erff(sx * 0.70710678118654752f));
    float g1 = 0.5f * sy * (1.0f + erff(sy * 0.70710678118654752f));
    *(float2*)&hT[i][c] = make_float2(g0, g1);
    #pragma unroll
    for (int r = 0; r < 5; ++r) {
      win[r][0] = win[r][1]; win[r][1] = win[r][2];
      win[r][2] = win[r][3]; win[r][3] = win[r][4];
    }
  }
  __syncthreads();

  {
    int o = tid & 15, px = tid >> 4;
    float acc = 0.f;
    #pragma unroll 4
    for (int c4 = 0; c4 < 128; ++c4) {
      float4 hv = *(const float4*)&hT[px][c4 * 4];
      float4 wv = *(const float4*)&wT[o][c4 * 4];
      acc += hv.x * wv.x + hv.y * wv.y + hv.z * wv.z + hv.w * wv.w;
    }
    ofs[px][o] = tanhf(acc) * 2.0f;
  }
  __syncthreads();

  if (tid < 128) {
    int px = tid >> 3, h = tid & 7;
    int n = y * 32 + x0 + px;
    float gx = -1.0f + 2.0f * (float)(x0 + px) / 31.0f;
    float gy = -1.0f + 2.0f * (float)y / 31.0f;
    float sx = fminf(fmaxf(gx + ofs[px][2 * h], -1.0f), 1.0f);
    float sy = fminf(fmaxf(gy + ofs[px][2 * h + 1], -1.0f), 1.0f);
    float2 pc;
    pc.x = (sx + 1.0f) * 16.0f - 0.5f;
    pc.y = (sy + 1.0f) * 16.0f - 0.5f;
    ((float2*)samp)[(size_t)(b * 8 + h) * 1024 + n] = pc;
  }
}

// ---------------------------------------------------------------------------
// Bilinear grid-sample of K and V -> Ks hi/lo [bh][1024][64], Vt [bh][64][1024]
// ---------------------------------------------------------------------------
__global__ __launch_bounds__(256) void grid_sample(
    const float* __restrict__ K, const float* __restrict__ V,
    const float* __restrict__ samp, ushort* __restrict__ Ksh,
    ushort* __restrict__ Ksl, ushort* __restrict__ Vt) {
  __shared__ ushort sV[64][72];
  int bh = blockIdx.y;
  int b = bh >> 3, h = bh & 7;
  int jb = blockIdx.x;
  int d = threadIdx.x & 63;
  for (int p = 0; p < 16; ++p) {
    int jl = p * 4 + (threadIdx.x >> 6);
    int j = jb * 64 + jl;
    float2 pc = ((const float2*)samp)[(size_t)bh * 1024 + j];
    float gx = pc.x, gy = pc.y;
    float x0 = floorf(gx), y0 = floorf(gy);
    float aK = 0.f, aV = 0.f;
    #pragma unroll
    for (int dy = 0; dy < 2; ++dy)
      #pragma unroll
      for (int dx = 0; dx < 2; ++dx) {
        float xi = x0 + (float)dx, yi = y0 + (float)dy;
        float wgt = (1.0f - fabsf(gx - xi)) * (1.0f - fabsf(gy - yi));
        if (xi >= 0.f && xi < 32.f && yi >= 0.f && yi < 32.f) {
          size_t base = ((size_t)b * 1024 + (int)yi * 32 + (int)xi) * 512 + h * 64 + d;
          aK += K[base] * wgt;
          aV += V[base] * wgt;
        }
      }
    ushort kh = f2bf(aK);
    size_t o = ((size_t)bh * 1024 + j) * 64 + d;
    Ksh[o] = kh;
    Ksl[o] = f2bf(aK - bf2f(kh));
    sV[jl][d] = f2bf(aV);
  }
  __syncthreads();
  int dd = threadIdx.x >> 2, c4 = threadIdx.x & 3;
  bf16x8 v0, v1;
  #pragma unroll
  for (int k = 0; k < 8; ++k) v0[k] = (short)sV[c4 * 16 + k][dd];
  #pragma unroll
  for (int k = 0; k < 8; ++k) v1[k] = (short)sV[c4 * 16 + 8 + k][dd];
  size_t o = ((size_t)bh * 64 + dd) * 1024 + jb * 64 + c4 * 16;
  *(bf16x8*)&Vt[o] = v0;
  *(bf16x8*)&Vt[o + 8] = v1;
}

// ---------------------------------------------------------------------------
// Bicubic taps + dense relative-position bias [1024][1024] (4 MB).
// ---------------------------------------------------------------------------
__device__ __forceinline__ void bicubic_taps(int i, float* w, int* idx) {
  const float a = -0.75f;
  float src = ((float)i + 0.5f) * 0.0625f - 0.5f;
  float fi = floorf(src);
  int i0 = (int)fi;
  float t = src - fi;
  #pragma unroll
  for (int k = -1; k <= 2; ++k) {
    float d = fabsf(t - (float)k);
    float wv;
    if (d <= 1.0f)
      wv = ((a + 2.0f) * d - (a + 3.0f)) * d * d + 1.0f;
    else if (d < 2.0f)
      wv = a * (((d - 5.0f) * d + 8.0f) * d - 4.0f);
    else
      wv = 0.0f;
    int ic = i0 + k;
    ic = ic < 0 ? 0 : (ic > 63 ? 63 : ic);
    w[k + 1] = wv;
    idx[k + 1] = ic;
  }
}

__global__ __launch_bounds__(256) void bias_kernel(
    const float* __restrict__ table, float* __restrict__ bias) {
  __shared__ float tab[225];
  int i = blockIdx.x;
  int tid = threadIdx.x;
  if (tid < 225) tab[tid] = table[tid];
  __syncthreads();
  float wA[4]; int iA[4];
  bicubic_taps(i, wA, iA);
  for (int j = tid; j < 1024; j += 256) {
    float wB[4]; int iB[4];
    bicubic_taps(j, wB, iB);
    float sum = 0.f;
    #pragma unroll
    for (int ka = 0; ka < 4; ++ka) {
      int pa = iA[ka];
      int py = pa >> 3, px = pa & 7;
      float wa = wA[ka];
      #pragma unroll
      for (int kb = 0; kb < 4; ++kb) {
        int qb = iB[kb];
        int qy = qb >> 3, qx = qb & 7;
        sum += wa * wB[kb] * tab[(py - qy + 7) * 15 + (px - qx + 7)];
      }
    }
    bias[(size_t)i * 1024 + j] = sum;
  }
}

// ---------------------------------------------------------------------------
// MFMA flash attention v5: 8 waves, in-block KV split (waves 0-3 keys
// [0,512), waves 4-7 keys [512,1024)), KVBLK=32 double-buffered per half ->
// 16 waves/CU (2x occupancy). Swapped QK^T, defer-max (THR=8), setprio
// around MFMA. Final flash-merge of the two halves through LDS.
// ---------------------------------------------------------------------------
__global__ __launch_bounds__(512, 4) void attn_mfma(
    const float* __restrict__ Q, const ushort* __restrict__ Kh,
    const ushort* __restrict__ Kl, const ushort* __restrict__ Vt,
    const float* __restrict__ bias, ushort* __restrict__ Oh,
    ushort* __restrict__ Ol) {
  __shared__ ushort sKh[2][2][2048];  // [buf][half][32 keys x 64]
  __shared__ ushort sKl[2][2][2048];
  __shared__ ushort sVt[2][2][2048];  // [buf][half][64 d x 32 keys]
  __shared__ ushort sP[8][640];       // per-wave [16 q][40] (pitch 40)

  int tid = threadIdx.x;
  int lane = tid & 63;
  int w = tid >> 6;        // 0..7
  int qg = w & 3;          // query group (16 q each)
  int kvh = w >> 2;        // KV half: 0 -> keys [0,512), 1 -> [512,1024)
  int l16 = lane & 15, lq = lane >> 4;
  int blk = blockIdx.x;
  int xcd = blk & 7;
  int rr = blk >> 3;
  int bh = ((rr & 3) << 3) + xcd;
  int i0 = (rr >> 2) * 64;
  int b = bh >> 3, h = bh & 7;

  // Q fragments (this wave's 16 rows), *0.125, hi/lo
  bf16x8 qh[2], ql[2];
  #pragma unroll
  for (int s = 0; s < 2; ++s) {
    const float* qp =
        Q + ((size_t)b * 1024 + i0 + qg * 16 + l16) * 512 + h * 64 + s * 32 + lq * 8;
    float4 va = *(const float4*)qp;
    float4 vb = *(const float4*)(qp + 4);
    float fv[8] = {va.x, va.y, va.z, va.w, vb.x, vb.y, vb.z, vb.w};
    #pragma unroll
    for (int j = 0; j < 8; ++j) {
      float f = fv[j] * 0.125f;
      ushort hb = f2bf(f);
      qh[s][j] = (short)hb;
      ql[s][j] = (short)f2bf(f - bf2f(hb));
    }
  }

  f32x4 oacc[4];
  f32x4 zero = {0.f, 0.f, 0.f, 0.f};
  #pragma unroll
  for (int n = 0; n < 4; ++n) oacc[n] = zero;
  float mq = -INFINITY, lsum = 0.f;  // per-query(l16) online state

  ushort* myP = sP[w];
  // staging geometry
  int krow = qg * 8 + (lane >> 3);              // K row this lane fetches
  int kslot = (lane & 7) ^ (krow & 7);          // pre-swizzled 16B slot
  int vrow = qg * 16 + (lane >> 2);             // V^T (d) row
  int vslot = (lane & 3) ^ (vrow & 3);
  size_t kbase = ((size_t)bh * 1024 + kvh * 512 + krow) * 64 + kslot * 8;
  size_t vbase = ((size_t)bh * 64 + vrow) * 1024 + kvh * 512 + vslot * 8;
  ushort* dKh0 = &sKh[0][kvh][qg * 8 * 64]; ushort* dKh1 = &sKh[1][kvh][qg * 8 * 64];
  ushort* dKl0 = &sKl[0][kvh][qg * 8 * 64]; ushort* dKl1 = &sKl[1][kvh][qg * 8 * 64];
  ushort* dVt0 = &sVt[0][kvh][qg * 16 * 32]; ushort* dVt1 = &sVt[1][kvh][qg * 16 * 32];
  const float* bprow = bias + (size_t)(i0 + qg * 16 + l16) * 1024 + kvh * 512;

  // ---- prologue: stage tile 0 into buf 0; preload bias(0) ----
  GLOAD16(Kh + kbase, dKh0);
  GLOAD16(Kl + kbase, dKl0);
  GLOAD16(Vt + vbase, dVt0);
  f32x4 bias_c[2];
  #pragma unroll
  for (int n = 0; n < 2; ++n)
    bias_c[n] = *(const f32x4*)&bprow[n * 16 + lq * 4];
  __syncthreads();

  int cur = 0;
  for (int t = 0; t < 16; ++t) {
    // ---- issue stage of tile t+1 into other buffer ----
    if (t < 15) {
      size_t off = (size_t)(t + 1) * 32;
      GLOAD16(Kh + kbase + off * 64, cur ? dKh0 : dKh1);
      GLOAD16(Kl + kbase + off * 64, cur ? dKl0 : dKl1);
      GLOAD16(Vt + vbase + off, cur ? dVt0 : dVt1);
    }
    f32x4 sacc[2];
    #pragma unroll
    for (int n = 0; n < 2; ++n) sacc[n] = bias_c[n];
    if (t < 15) {
      #pragma unroll
      for (int n = 0; n < 2; ++n)
        bias_c[n] = *(const f32x4*)&bprow[(t + 1) * 32 + n * 16 + lq * 4];
    }
    // ---- SWAPPED QK^T: A = K rows (32 keys), B = Q regs -> S^T ----
    const ushort* kh_t = sKh[cur][kvh];
    const ushort* kl_t = sKl[cur][kvh];
    __builtin_amdgcn_s_setprio(1);
    #pragma unroll
    for (int ks = 0; ks < 2; ++ks) {
      int cslot = ((ks * 4 + lq) ^ (l16 & 7)) * 8;
      #pragma unroll
      for (int n = 0; n < 2; ++n) {
        int brow = (n * 16 + l16) * 64;
        bf16x8 aH = *(const bf16x8*)&kh_t[brow + cslot];
        bf16x8 aL = *(const bf16x8*)&kl_t[brow + cslot];
        sacc[n] = MFMA16(aH, qh[ks], sacc[n]);
        sacc[n] = MFMA16(aL, qh[ks], sacc[n]);
        sacc[n] = MFMA16(aH, ql[ks], sacc[n]);
      }
    }
    __builtin_amdgcn_s_setprio(0);
    // ---- softmax: lane holds 8 scores of query l16 ----
    float mt = fmaxf(fmaxf(fmaxf(sacc[0][0], sacc[0][1]), fmaxf(sacc[0][2], sacc[0][3])),
                     fmaxf(fmaxf(sacc[1][0], sacc[1][1]), fmaxf(sacc[1][2], sacc[1][3])));
    mt = fmaxf(mt, __shfl_xor(mt, 16));
    mt = fmaxf(mt, __shfl_xor(mt, 32));
    if (!__all(mt <= mq + 8.0f)) {  // defer-max: rescale only on real growth
      float mn = fmaxf(mq, mt);
      float sc = __expf(mq - mn);
      mq = mn;
      lsum *= sc;
      float scq[4];
      #pragma unroll
      for (int r = 0; r < 4; ++r) scq[r] = __shfl(sc, lq * 4 + r);
      #pragma unroll
      for (int n = 0; n < 4; ++n)
        #pragma unroll
        for (int r = 0; r < 4; ++r) oacc[n][r] *= scq[r];
    }
    float ts = 0.f;
    #pragma unroll
    for (int n = 0; n < 2; ++n) {
      float p0 = __expf(sacc[n][0] - mq);
      float p1 = __expf(sacc[n][1] - mq);
      float p2 = __expf(sacc[n][2] - mq);
      float p3 = __expf(sacc[n][3] - mq);
      ts += (p0 + p1) + (p2 + p3);
      uint2 u = make_uint2(pk_bf16(p0, p1), pk_bf16(p2, p3));
      *(uint2*)&myP[l16 * 40 + n * 16 + lq * 4] = u;
    }
    ts += __shfl_xor(ts, 16);
    ts += __shfl_xor(ts, 32);
    lsum += ts;
    // ---- PV: A = P [16q][32k], B = V^T [16d][32k] (K=32, one MFMA per n) ----
    bf16x8 pa = *(const bf16x8*)&myP[l16 * 40 + lq * 8];
    const ushort* vt_t = sVt[cur][kvh];
    __builtin_amdgcn_s_setprio(1);
    #pragma unroll
    for (int n = 0; n < 4; ++n) {
      int row = n * 16 + l16;
      bf16x8 bv = *(const bf16x8*)&vt_t[row * 32 + ((lq ^ (row & 3)) * 8)];
      oacc[n] = MFMA16(pa, bv, oacc[n]);
    }
    __builtin_amdgcn_s_setprio(0);
    __syncthreads();  // drains stage(t+1); all waves done with buf cur
    cur ^= 1;
  }

  // ---- flash-merge of the two halves via LDS ----
  float* mO = (float*)sKh;   // 4 waves x 64 lanes x 16 f32 = 16 KB
  float* mML = (float*)sKl;  // 4 waves x 64 lanes x 2 f32
  if (w >= 4) {
    int base = ((w - 4) * 64 + lane) * 16;
    #pragma unroll
    for (int n = 0; n < 4; ++n)
      #pragma unroll
      for (int r = 0; r < 4; ++r) mO[base + n * 4 + r] = oacc[n][r];
    mML[((w - 4) * 64 + lane) * 2 + 0] = mq;
    mML[((w - 4) * 64 + lane) * 2 + 1] = lsum;
  }
  __syncthreads();
  if (w < 4) {
    float mB = mML[(w * 64 + lane) * 2 + 0];
    float lB = mML[(w * 64 + lane) * 2 + 1];
    float mS = fmaxf(mq, mB);
    float fA = __expf(mq - mS), fB = __expf(mB - mS);
    float linv = 1.0f / (lsum * fA + lB * fB);
    float cAv = fA * linv, cBv = fB * linv;
    float cA[4], cB[4];
    #pragma unroll
    for (int r = 0; r < 4; ++r) {
      cA[r] = __shfl(cAv, lq * 4 + r);
      cB[r] = __shfl(cBv, lq * 4 + r);
    }
    int base = (w * 64 + lane) * 16;
    #pragma unroll
    for (int r = 0; r < 4; ++r) {
      int qr = i0 + qg * 16 + lq * 4 + r;
      #pragma unroll
      for (int n = 0; n < 4; ++n) {
        float v = oacc[n][r] * cA[r] + mO[base + n * 4 + r] * cB[r];
        ushort hb = f2bf(v);
        size_t o = ((size_t)b * 1024 + qr) * 512 + h * 64 + n * 16 + l16;
        Oh[o] = hb;
        Ol[o] = f2bf(v - bf2f(hb));
      }
    }
  }
}

// ---------------------------------------------------------------------------
extern "C" void kernel_launch(void* const* d_in, const int* in_sizes, int n_in,
                              void* d_out, int out_size, void* d_ws, size_t ws_size,
                              hipStream_t stream) {
  const float* x     = (const float*)d_in[0];
  const float* q_w   = (const float*)d_in[1];
  const float* q_b   = (const float*)d_in[2];
  const float* k_w   = (const float*)d_in[3];
  const float* k_b   = (const float*)d_in[4];
  const float* v_w   = (const float*)d_in[5];
  const float* v_b   = (const float*)d_in[6];
  const float* o_w   = (const float*)d_in[7];
  const float* o_b   = (const float*)d_in[8];
  const float* dw_w  = (const float*)d_in[9];
  const float* dw_b  = (const float*)d_in[10];
  const float* off_w = (const float*)d_in[11];
  const float* btab  = (const float*)d_in[12];

  float* ws = (float*)d_ws;
  const size_t SZ = (size_t)4 * 1024 * 512;  // 2M elements
  float* Q    = ws;
  float* K    = ws + SZ;
  float* V    = ws + 2 * SZ;
  float* bias = ws + 3 * SZ;                 // 1M floats (4 MB)
  float* samp = ws + 3 * SZ + 1048576;       // 65536 floats

  ushort* u = (ushort*)(samp + 65536);
  ushort* Xhi  = u;                          // 2M each
  ushort* Xlo  = Xhi + SZ;
  ushort* Wq_h = Xlo + SZ;                   // 256K each, 8 buffers
  ushort* Wq_l = Wq_h + 262144;
  ushort* Wk_h = Wq_h + 2 * 262144;
  ushort* Wk_l = Wq_h + 3 * 262144;
  ushort* Wv_h = Wq_h + 4 * 262144;
  ushort* Wv_l = Wq_h + 5 * 262144;
  ushort* Wo_h = Wq_h + 6 * 262144;
  ushort* Wo_l = Wq_h + 7 * 262144;
  ushort* Ksh  = Wq_h + 8 * 262144;          // 2M each
  ushort* Ksl  = Ksh + SZ;
  ushort* Vtr  = Ksl + SZ;
  ushort* Aoh  = Vtr + SZ;
  ushort* Aol  = Aoh + SZ;
  float* dwT   = (float*)(Aol + SZ);         // 25*512 floats

  split_kernel<<<2048, 256, 0, stream>>>(x, Xhi, Xlo, 524288);
  prep_weights<<<1026, 256, 0, stream>>>(q_w, k_w, v_w, o_w, dw_w, Wq_h, Wq_l,
                                         Wk_h, Wk_l, Wv_h, Wv_l, Wo_h, Wo_l, dwT);

  gemm_qkv<<<dim3(24, 32), 256, 0, stream>>>(Xhi, Xlo, Wq_h, Wq_l, Wk_h, Wk_l,
                                             Wv_h, Wv_l, q_b, k_b, v_b, Q, K, V);

  offset_net2<<<dim3(2, 32, 4), 256, 0, stream>>>(x, dwT, dw_b, off_w, samp);
  bias_kernel<<<1024, 256, 0, stream>>>(btab, bias);
  grid_sample<<<dim3(16, 32), 256, 0, stream>>>(K, V, samp, Ksh, Ksl, Vtr);

  attn_mfma<<<512, 512, 0, stream>>>(Q, Ksh, Ksl, Vtr, bias, Aoh, Aol);

  gemm_mfma<<<dim3(8, 32), 256, 0, stream>>>(Aoh, Aol, Wo_h, Wo_l, o_b,
                                             (float*)d_out);
}

// Round 9
// 120.931 us; speedup vs baseline: 1.3478x; 1.1279x over previous
//
#include <hip/hip_runtime.h>
#include <math.h>

typedef unsigned short ushort;
typedef __attribute__((ext_vector_type(8))) short bf16x8;
typedef __attribute__((ext_vector_type(4))) float f32x4;

#define MFMA16(a, b, c) __builtin_amdgcn_mfma_f32_16x16x32_bf16(a, b, c, 0, 0, 0)
#define GLOAD16(g, l)                                                   \
  __builtin_amdgcn_global_load_lds(                                     \
      (const __attribute__((address_space(1))) unsigned int*)(g),       \
      (__attribute__((address_space(3))) unsigned int*)(l), 16, 0, 0)

__device__ __forceinline__ ushort f2bf(float f) {
  unsigned u = __float_as_uint(f);
  u += 0x7FFFu + ((u >> 16) & 1u);  // RNE
  return (ushort)(u >> 16);
}
__device__ __forceinline__ float bf2f(ushort b) {
  return __uint_as_float(((unsigned)b) << 16);
}
__device__ __forceinline__ unsigned pk_bf16(float a, float b) {
  unsigned u;
  asm("v_cvt_pk_bf16_f32 %0, %1, %2" : "=v"(u) : "v"(a), "v"(b));
  return u;
}

// ---------------------------------------------------------------------------
// x -> bf16 (hi only): single-pass QKV GEMM needs no lo part.
// ---------------------------------------------------------------------------
__global__ __launch_bounds__(256) void split_hi(
    const float* __restrict__ in, ushort* __restrict__ hi, int n4) {
  int i = blockIdx.x * 256 + threadIdx.x;
  if (i >= n4) return;
  float4 v = ((const float4*)in)[i];
  ushort4 h;
  h.x = f2bf(v.x); h.y = f2bf(v.y); h.z = f2bf(v.z); h.w = f2bf(v.w);
  ((ushort4*)hi)[i] = h;
}

// ---------------------------------------------------------------------------
// Weight prep: q/k/v -> bf16 hi only; o_w -> hi/lo; + dw transpose.
// ---------------------------------------------------------------------------
__global__ __launch_bounds__(256) void prep_weights(
    const float* __restrict__ q_w, const float* __restrict__ k_w,
    const float* __restrict__ v_w, const float* __restrict__ o_w,
    const float* __restrict__ dw_w, ushort* __restrict__ Wq,
    ushort* __restrict__ Wk, ushort* __restrict__ Wv,
    ushort* __restrict__ Woh, ushort* __restrict__ Wol,
    float* __restrict__ dwT) {
  int blk = blockIdx.x;
  if (blk < 1024) {
    int grp = blk >> 8;
    int i = (blk & 255) * 256 + threadIdx.x;
    if (grp < 3) {
      const float* in = grp == 0 ? q_w : grp == 1 ? k_w : v_w;
      ushort* hi = grp == 0 ? Wq : grp == 1 ? Wk : Wv;
      float4 v = ((const float4*)in)[i];
      ushort4 h;
      h.x = f2bf(v.x); h.y = f2bf(v.y); h.z = f2bf(v.z); h.w = f2bf(v.w);
      ((ushort4*)hi)[i] = h;
    } else {
      float4 v = ((const float4*)o_w)[i];
      ushort4 h, l;
      h.x = f2bf(v.x); l.x = f2bf(v.x - bf2f(h.x));
      h.y = f2bf(v.y); l.y = f2bf(v.y - bf2f(h.y));
      h.z = f2bf(v.z); l.z = f2bf(v.z - bf2f(h.z));
      h.w = f2bf(v.w); l.w = f2bf(v.w - bf2f(h.w));
      ((ushort4*)Woh)[i] = h;
      ((ushort4*)Wol)[i] = l;
    }
  } else {
    int c = (blk - 1024) * 256 + threadIdx.x;
    #pragma unroll
    for (int k = 0; k < 25; ++k) dwT[k * 512 + c] = dw_w[c * 25 + k];
  }
}

// ---------------------------------------------------------------------------
// Fused QKV GEMM, single-pass bf16: Yo[4096,512] = bf16((X@W^T + b)*scale).
// Tile 128x64, BK=64, 256 threads (4 waves 2x2). Q gets scale=0.125.
// ---------------------------------------------------------------------------
__global__ __launch_bounds__(256) void gemm_qkv(
    const ushort* __restrict__ X, const ushort* __restrict__ Wq,
    const ushort* __restrict__ Wk, const ushort* __restrict__ Wv,
    const float* __restrict__ b0, const float* __restrict__ b1,
    const float* __restrict__ b2, ushort* __restrict__ Qo,
    ushort* __restrict__ Ko, ushort* __restrict__ Vo) {
  __shared__ ushort lds[12288];  // A[128*64] + B[64*64]
  ushort* sA = lds;
  ushort* sB = lds + 8192;
  int which = blockIdx.x >> 3;
  int n0 = (blockIdx.x & 7) * 64;
  int m0 = blockIdx.y * 128;
  const ushort* W; const float* bb; ushort* Y; float scale;
  if (which == 0)      { W = Wq; bb = b0; Y = Qo; scale = 0.125f; }
  else if (which == 1) { W = Wk; bb = b1; Y = Ko; scale = 1.0f; }
  else                 { W = Wv; bb = b2; Y = Vo; scale = 1.0f; }

  int tid = threadIdx.x;
  int lane = tid & 63;
  int w = tid >> 6;
  int wr = (w >> 1) * 64;
  int wc = (w & 1) * 32;
  int l8r = lane >> 3;
  int sll = ((lane & 7) ^ l8r) << 3;
  int l16 = lane & 15, lq = lane >> 4;

  f32x4 acc[4][2];
  f32x4 zero = {0.f, 0.f, 0.f, 0.f};
  #pragma unroll
  for (int m = 0; m < 4; ++m)
    #pragma unroll
    for (int n = 0; n < 2; ++n) acc[m][n] = zero;

  for (int kt = 0; kt < 8; ++kt) {
    int kk = kt * 64;
    __syncthreads();
    #pragma unroll
    for (int q = 0; q < 4; ++q) {
      int ci = w * 4 + q;
      GLOAD16(X + (size_t)(m0 + ci * 8 + l8r) * 512 + kk + sll, sA + ci * 512);
    }
    #pragma unroll
    for (int q = 0; q < 2; ++q) {
      int ci = w * 2 + q;
      GLOAD16(W + (size_t)(n0 + ci * 8 + l8r) * 512 + kk + sll, sB + ci * 512);
    }
    __syncthreads();
    #pragma unroll
    for (int ks = 0; ks < 2; ++ks) {
      int slot = ks * 4 + lq;
      bf16x8 a[4], bvv[2];
      #pragma unroll
      for (int m = 0; m < 4; ++m) {
        int r = wr + m * 16 + l16;
        a[m] = *(const bf16x8*)&sA[r * 64 + ((slot ^ (r & 7)) << 3)];
      }
      #pragma unroll
      for (int n = 0; n < 2; ++n) {
        int r = wc + n * 16 + l16;
        bvv[n] = *(const bf16x8*)&sB[r * 64 + ((slot ^ (r & 7)) << 3)];
      }
      #pragma unroll
      for (int m = 0; m < 4; ++m)
        #pragma unroll
        for (int n = 0; n < 2; ++n)
          acc[m][n] = MFMA16(a[m], bvv[n], acc[m][n]);
    }
  }
  #pragma unroll
  for (int n = 0; n < 2; ++n) {
    int col = n0 + wc + n * 16 + l16;
    float bv = bb[col];
    #pragma unroll
    for (int m = 0; m < 4; ++m) {
      #pragma unroll
      for (int j = 0; j < 4; ++j) {
        int row = m0 + wr + m * 16 + lq * 4 + j;
        Y[(size_t)row * 512 + col] = f2bf((acc[m][n][j] + bv) * scale);
      }
    }
  }
}

// ---------------------------------------------------------------------------
// O-proj GEMM (3-pass hi/lo, fp32 out) — unchanged proven body.
// ---------------------------------------------------------------------------
__global__ __launch_bounds__(256) void gemm_mfma(
    const ushort* __restrict__ Ahi, const ushort* __restrict__ Alo,
    const ushort* __restrict__ Bhi, const ushort* __restrict__ Blo,
    const float* __restrict__ bias, float* __restrict__ Y) {
  __shared__ ushort lds[24576];
  ushort* sAhi = lds;
  ushort* sAlo = lds + 8192;
  ushort* sBhi = lds + 16384;
  ushort* sBlo = lds + 20480;
  int m0 = blockIdx.y * 128, n0 = blockIdx.x * 64;
  int tid = threadIdx.x;
  int lane = tid & 63;
  int w = tid >> 6;
  int wr = (w >> 1) * 64;
  int wc = (w & 1) * 32;
  int l8r = lane >> 3;
  int sll = ((lane & 7) ^ l8r) << 3;
  int l16 = lane & 15, lq = lane >> 4;

  f32x4 acc[4][2];
  f32x4 zero = {0.f, 0.f, 0.f, 0.f};
  #pragma unroll
  for (int m = 0; m < 4; ++m)
    #pragma unroll
    for (int n = 0; n < 2; ++n) acc[m][n] = zero;

  for (int kt = 0; kt < 8; ++kt) {
    int kk = kt * 64;
    __syncthreads();
    #pragma unroll
    for (int q = 0; q < 4; ++q) {
      int ci = w * 4 + q;
      size_t go = (size_t)(m0 + ci * 8 + l8r) * 512 + kk + sll;
      GLOAD16(Ahi + go, sAhi + ci * 512);
      GLOAD16(Alo + go, sAlo + ci * 512);
    }
    #pragma unroll
    for (int q = 0; q < 2; ++q) {
      int ci = w * 2 + q;
      size_t go = (size_t)(n0 + ci * 8 + l8r) * 512 + kk + sll;
      GLOAD16(Bhi + go, sBhi + ci * 512);
      GLOAD16(Blo + go, sBlo + ci * 512);
    }
    __syncthreads();
    #pragma unroll
    for (int ks = 0; ks < 2; ++ks) {
      int slot = ks * 4 + lq;
      bf16x8 ah[4], al[4], bh[2], bl[2];
      #pragma unroll
      for (int m = 0; m < 4; ++m) {
        int r = wr + m * 16 + l16;
        int ph = (slot ^ (r & 7)) << 3;
        ah[m] = *(const bf16x8*)&sAhi[r * 64 + ph];
        al[m] = *(const bf16x8*)&sAlo[r * 64 + ph];
      }
      #pragma unroll
      for (int n = 0; n < 2; ++n) {
        int r = wc + n * 16 + l16;
        int ph = (slot ^ (r & 7)) << 3;
        bh[n] = *(const bf16x8*)&sBhi[r * 64 + ph];
        bl[n] = *(const bf16x8*)&sBlo[r * 64 + ph];
      }
      #pragma unroll
      for (int m = 0; m < 4; ++m)
        #pragma unroll
        for (int n = 0; n < 2; ++n) {
          acc[m][n] = MFMA16(ah[m], bh[n], acc[m][n]);
          acc[m][n] = MFMA16(ah[m], bl[n], acc[m][n]);
          acc[m][n] = MFMA16(al[m], bh[n], acc[m][n]);
        }
    }
  }
  #pragma unroll
  for (int n = 0; n < 2; ++n) {
    int col = n0 + wc + n * 16 + l16;
    float bv = bias[col];
    #pragma unroll
    for (int m = 0; m < 4; ++m) {
      #pragma unroll
      for (int j = 0; j < 4; ++j) {
        int row = m0 + wr + m * 16 + lq * 4 + j;
        Y[(size_t)row * 512 + col] = acc[m][n][j] + bv;
      }
    }
  }
}

// ---------------------------------------------------------------------------
// Offset network (register sliding-window depthwise conv). Unchanged.
// ---------------------------------------------------------------------------
__global__ __launch_bounds__(256) void offset_net2(
    const float* __restrict__ x, const float* __restrict__ dwT,
    const float* __restrict__ dw_b, const float* __restrict__ off_w,
    float* __restrict__ samp) {
  __shared__ float wT[16][516];
  __shared__ float hT[16][516];
  __shared__ float ofs[16][16];
  int x0 = blockIdx.x * 16;
  int y = blockIdx.y;
  int b = blockIdx.z;
  int tid = threadIdx.x;

  for (int e = tid; e < 2048; e += 256) {
    int o = e >> 7, c4 = e & 127;
    *(float4*)&wT[o][c4 * 4] = *(const float4*)&off_w[o * 512 + c4 * 4];
  }

  int c = tid * 2;
  float2 dwv[25];
  #pragma unroll
  for (int k = 0; k < 25; ++k) dwv[k] = *(const float2*)&dwT[k * 512 + c];
  float2 cb = *(const float2*)&dw_b[c];

  const float* xb = x + (size_t)b * 1024 * 512 + c;
  bool rv[5];
  #pragma unroll
  for (int r = 0; r < 5; ++r) {
    int yy = y - 2 + r;
    rv[r] = (yy >= 0 && yy < 32);
  }
  float2 win[5][5];
  #pragma unroll
  for (int j = 0; j < 4; ++j) {
    int xc = x0 - 2 + j;
    bool cvld = (xc >= 0 && xc < 32);
    #pragma unroll
    for (int r = 0; r < 5; ++r) {
      win[r][j] = (rv[r] && cvld)
          ? *(const float2*)&xb[(size_t)((y - 2 + r) * 32 + xc) * 512]
          : make_float2(0.f, 0.f);
    }
  }
  #pragma unroll
  for (int i = 0; i < 16; ++i) {
    int xc = x0 + i + 2;
    bool cvld = (xc < 32);
    #pragma unroll
    for (int r = 0; r < 5; ++r) {
      win[r][4] = (rv[r] && cvld)
          ? *(const float2*)&xb[(size_t)((y - 2 + r) * 32 + xc) * 512]
          : make_float2(0.f, 0.f);
    }
    float sx = cb.x, sy = cb.y;
    #pragma unroll
    for (int r = 0; r < 5; ++r)
      #pragma unroll
      for (int j = 0; j < 5; ++j) {
        sx += win[r][j].x * dwv[r * 5 + j].x;
        sy += win[r][j].y * dwv[r * 5 + j].y;
      }
    float g0 = 0.5f * sx * (1.0f + erff(sx * 0.70710678118654752f));
    float g1 = 0.5f * sy * (1.0f + erff(sy * 0.70710678118654752f));
    *(float2*)&hT[i][c] = make_float2(g0, g1);
    #pragma unroll
    for (int r = 0; r < 5; ++r) {
      win[r][0] = win[r][1]; win[r][1] = win[r][2];
      win[r][2] = win[r][3]; win[r][3] = win[r][4];
    }
  }
  __syncthreads();

  {
    int o = tid & 15, px = tid >> 4;
    float acc = 0.f;
    #pragma unroll 4
    for (int c4 = 0; c4 < 128; ++c4) {
      float4 hv = *(const float4*)&hT[px][c4 * 4];
      float4 wv = *(const float4*)&wT[o][c4 * 4];
      acc += hv.x * wv.x + hv.y * wv.y + hv.z * wv.z + hv.w * wv.w;
    }
    ofs[px][o] = tanhf(acc) * 2.0f;
  }
  __syncthreads();

  if (tid < 128) {
    int px = tid >> 3, h = tid & 7;
    int n = y * 32 + x0 + px;
    float gx = -1.0f + 2.0f * (float)(x0 + px) / 31.0f;
    float gy = -1.0f + 2.0f * (float)y / 31.0f;
    float sx = fminf(fmaxf(gx + ofs[px][2 * h], -1.0f), 1.0f);
    float sy = fminf(fmaxf(gy + ofs[px][2 * h + 1], -1.0f), 1.0f);
    float2 pc;
    pc.x = (sx + 1.0f) * 16.0f - 0.5f;
    pc.y = (sy + 1.0f) * 16.0f - 0.5f;
    ((float2*)samp)[(size_t)(b * 8 + h) * 1024 + n] = pc;
  }
}

// ---------------------------------------------------------------------------
// Bilinear grid-sample of bf16 K,V -> Ks [bh][1024][64] bf16,
// Vt [bh][64 d][1024 key] bf16.
// ---------------------------------------------------------------------------
__global__ __launch_bounds__(256) void grid_sample(
    const ushort* __restrict__ K, const ushort* __restrict__ V,
    const float* __restrict__ samp, ushort* __restrict__ Ks,
    ushort* __restrict__ Vt) {
  __shared__ ushort sV[64][72];
  int bh = blockIdx.y;
  int b = bh >> 3, h = bh & 7;
  int jb = blockIdx.x;
  int d = threadIdx.x & 63;
  for (int p = 0; p < 16; ++p) {
    int jl = p * 4 + (threadIdx.x >> 6);
    int j = jb * 64 + jl;
    float2 pc = ((const float2*)samp)[(size_t)bh * 1024 + j];
    float gx = pc.x, gy = pc.y;
    float x0 = floorf(gx), y0 = floorf(gy);
    float aK = 0.f, aV = 0.f;
    #pragma unroll
    for (int dy = 0; dy < 2; ++dy)
      #pragma unroll
      for (int dx = 0; dx < 2; ++dx) {
        float xi = x0 + (float)dx, yi = y0 + (float)dy;
        float wgt = (1.0f - fabsf(gx - xi)) * (1.0f - fabsf(gy - yi));
        if (xi >= 0.f && xi < 32.f && yi >= 0.f && yi < 32.f) {
          size_t base = ((size_t)b * 1024 + (int)yi * 32 + (int)xi) * 512 + h * 64 + d;
          aK += bf2f(K[base]) * wgt;
          aV += bf2f(V[base]) * wgt;
        }
      }
    Ks[((size_t)bh * 1024 + j) * 64 + d] = f2bf(aK);
    sV[jl][d] = f2bf(aV);
  }
  __syncthreads();
  int dd = threadIdx.x >> 2, c4 = threadIdx.x & 3;
  bf16x8 v0, v1;
  #pragma unroll
  for (int k = 0; k < 8; ++k) v0[k] = (short)sV[c4 * 16 + k][dd];
  #pragma unroll
  for (int k = 0; k < 8; ++k) v1[k] = (short)sV[c4 * 16 + 8 + k][dd];
  size_t o = ((size_t)bh * 64 + dd) * 1024 + jb * 64 + c4 * 16;
  *(bf16x8*)&Vt[o] = v0;
  *(bf16x8*)&Vt[o + 8] = v1;
}

// ---------------------------------------------------------------------------
// Bicubic taps + dense relative-position bias [1024][1024] (4 MB).
// ---------------------------------------------------------------------------
__device__ __forceinline__ void bicubic_taps(int i, float* w, int* idx) {
  const float a = -0.75f;
  float src = ((float)i + 0.5f) * 0.0625f - 0.5f;
  float fi = floorf(src);
  int i0 = (int)fi;
  float t = src - fi;
  #pragma unroll
  for (int k = -1; k <= 2; ++k) {
    float d = fabsf(t - (float)k);
    float wv;
    if (d <= 1.0f)
      wv = ((a + 2.0f) * d - (a + 3.0f)) * d * d + 1.0f;
    else if (d < 2.0f)
      wv = a * (((d - 5.0f) * d + 8.0f) * d - 4.0f);
    else
      wv = 0.0f;
    int ic = i0 + k;
    ic = ic < 0 ? 0 : (ic > 63 ? 63 : ic);
    w[k + 1] = wv;
    idx[k + 1] = ic;
  }
}

__global__ __launch_bounds__(256) void bias_kernel(
    const float* __restrict__ table, float* __restrict__ bias) {
  __shared__ float tab[225];
  int i = blockIdx.x;
  int tid = threadIdx.x;
  if (tid < 225) tab[tid] = table[tid];
  __syncthreads();
  float wA[4]; int iA[4];
  bicubic_taps(i, wA, iA);
  for (int j = tid; j < 1024; j += 256) {
    float wB[4]; int iB[4];
    bicubic_taps(j, wB, iB);
    float sum = 0.f;
    #pragma unroll
    for (int ka = 0; ka < 4; ++ka) {
      int pa = iA[ka];
      int py = pa >> 3, px = pa & 7;
      float wa = wA[ka];
      #pragma unroll
      for (int kb = 0; kb < 4; ++kb) {
        int qb = iB[kb];
        int qy = qb >> 3, qx = qb & 7;
        sum += wa * wB[kb] * tab[(py - qy + 7) * 15 + (px - qx + 7)];
      }
    }
    bias[(size_t)i * 1024 + j] = sum;
  }
}

// ---------------------------------------------------------------------------
// MFMA flash attention v6: single-bf16 Q/K/V. 8 waves, KV split in block,
// KVBLK=32 double-buffered, swapped QK^T (1 MFMA/pos), defer-max, setprio.
// LDS ~42KB -> 3 blocks/CU (24 waves).
// ---------------------------------------------------------------------------
__global__ __launch_bounds__(512, 6) void attn_mfma(
    const ushort* __restrict__ Qh, const ushort* __restrict__ Ks,
    const ushort* __restrict__ Vt, const float* __restrict__ bias,
    ushort* __restrict__ Oh, ushort* __restrict__ Ol) {
  __shared__ ushort sK[2][2][2048];   // [buf][half][32 keys x 64]
  __shared__ ushort sVt[2][2][2048];  // [buf][half][64 d x 32 keys]
  __shared__ ushort sP[8][640];       // per-wave [16 q][40]

  int tid = threadIdx.x;
  int lane = tid & 63;
  int w = tid >> 6;        // 0..7
  int qg = w & 3;          // query group (16 q)
  int kvh = w >> 2;        // KV half
  int l16 = lane & 15, lq = lane >> 4;
  int blk = blockIdx.x;
  int xcd = blk & 7;
  int rr = blk >> 3;
  int bh = ((rr & 3) << 3) + xcd;
  int i0 = (rr >> 2) * 64;
  int b = bh >> 3, h = bh & 7;

  // Q fragments: direct bf16 loads (pre-scaled by 0.125 in gemm_qkv)
  bf16x8 qh[2];
  #pragma unroll
  for (int s = 0; s < 2; ++s)
    qh[s] = *(const bf16x8*)&Qh[((size_t)b * 1024 + i0 + qg * 16 + l16) * 512 +
                                h * 64 + s * 32 + lq * 8];

  f32x4 oacc[4];
  f32x4 zero = {0.f, 0.f, 0.f, 0.f};
  #pragma unroll
  for (int n = 0; n < 4; ++n) oacc[n] = zero;
  float mq = -INFINITY, lsum = 0.f;

  ushort* myP = sP[w];
  int krow = qg * 8 + (lane >> 3);
  int kslot = (lane & 7) ^ (krow & 7);
  int vrow = qg * 16 + (lane >> 2);
  int vslot = (lane & 3) ^ (vrow & 3);
  size_t kbase = ((size_t)bh * 1024 + kvh * 512 + krow) * 64 + kslot * 8;
  size_t vbase = ((size_t)bh * 64 + vrow) * 1024 + kvh * 512 + vslot * 8;
  ushort* dK0 = &sK[0][kvh][qg * 8 * 64];  ushort* dK1 = &sK[1][kvh][qg * 8 * 64];
  ushort* dV0 = &sVt[0][kvh][qg * 16 * 32]; ushort* dV1 = &sVt[1][kvh][qg * 16 * 32];
  const float* bprow = bias + (size_t)(i0 + qg * 16 + l16) * 1024 + kvh * 512;

  GLOAD16(Ks + kbase, dK0);
  GLOAD16(Vt + vbase, dV0);
  f32x4 bias_c[2];
  #pragma unroll
  for (int n = 0; n < 2; ++n)
    bias_c[n] = *(const f32x4*)&bprow[n * 16 + lq * 4];
  __syncthreads();

  int cur = 0;
  for (int t = 0; t < 16; ++t) {
    if (t < 15) {
      size_t off = (size_t)(t + 1) * 32;
      GLOAD16(Ks + kbase + off * 64, cur ? dK0 : dK1);
      GLOAD16(Vt + vbase + off, cur ? dV0 : dV1);
    }
    f32x4 sacc[2];
    #pragma unroll
    for (int n = 0; n < 2; ++n) sacc[n] = bias_c[n];
    if (t < 15) {
      #pragma unroll
      for (int n = 0; n < 2; ++n)
        bias_c[n] = *(const f32x4*)&bprow[(t + 1) * 32 + n * 16 + lq * 4];
    }
    // SWAPPED QK^T, single pass: A = K rows, B = Q regs -> S^T
    const ushort* k_t = sK[cur][kvh];
    __builtin_amdgcn_s_setprio(1);
    #pragma unroll
    for (int ks = 0; ks < 2; ++ks) {
      int cslot = ((ks * 4 + lq) ^ (l16 & 7)) * 8;
      #pragma unroll
      for (int n = 0; n < 2; ++n) {
        bf16x8 aK = *(const bf16x8*)&k_t[(n * 16 + l16) * 64 + cslot];
        sacc[n] = MFMA16(aK, qh[ks], sacc[n]);
      }
    }
    __builtin_amdgcn_s_setprio(0);
    // softmax: lane owns 8 scores of query l16
    float mt = fmaxf(fmaxf(fmaxf(sacc[0][0], sacc[0][1]), fmaxf(sacc[0][2], sacc[0][3])),
                     fmaxf(fmaxf(sacc[1][0], sacc[1][1]), fmaxf(sacc[1][2], sacc[1][3])));
    mt = fmaxf(mt, __shfl_xor(mt, 16));
    mt = fmaxf(mt, __shfl_xor(mt, 32));
    if (!__all(mt <= mq + 8.0f)) {
      float mn = fmaxf(mq, mt);
      float sc = __expf(mq - mn);
      mq = mn;
      lsum *= sc;
      float scq[4];
      #pragma unroll
      for (int r = 0; r < 4; ++r) scq[r] = __shfl(sc, lq * 4 + r);
      #pragma unroll
      for (int n = 0; n < 4; ++n)
        #pragma unroll
        for (int r = 0; r < 4; ++r) oacc[n][r] *= scq[r];
    }
    float ts = 0.f;
    #pragma unroll
    for (int n = 0; n < 2; ++n) {
      float p0 = __expf(sacc[n][0] - mq);
      float p1 = __expf(sacc[n][1] - mq);
      float p2 = __expf(sacc[n][2] - mq);
      float p3 = __expf(sacc[n][3] - mq);
      ts += (p0 + p1) + (p2 + p3);
      uint2 u = make_uint2(pk_bf16(p0, p1), pk_bf16(p2, p3));
      *(uint2*)&myP[l16 * 40 + n * 16 + lq * 4] = u;
    }
    ts += __shfl_xor(ts, 16);
    ts += __shfl_xor(ts, 32);
    lsum += ts;
    // PV: A = P [16q][32k], B = V^T [16d][32k]
    bf16x8 pa = *(const bf16x8*)&myP[l16 * 40 + lq * 8];
    const ushort* vt_t = sVt[cur][kvh];
    __builtin_amdgcn_s_setprio(1);
    #pragma unroll
    for (int n = 0; n < 4; ++n) {
      int row = n * 16 + l16;
      bf16x8 bv = *(const bf16x8*)&vt_t[row * 32 + ((lq ^ (row & 3)) * 8)];
      oacc[n] = MFMA16(pa, bv, oacc[n]);
    }
    __builtin_amdgcn_s_setprio(0);
    __syncthreads();
    cur ^= 1;
  }

  // flash-merge of the two halves via LDS (reuse sK for O, sVt for m/l)
  float* mO = (float*)sK;    // 4 waves x 64 lanes x 16 f32 = 16 KB
  float* mML = (float*)sVt;  // 4 waves x 64 lanes x 2 f32
  if (w >= 4) {
    int base = ((w - 4) * 64 + lane) * 16;
    #pragma unroll
    for (int n = 0; n < 4; ++n)
      #pragma unroll
      for (int r = 0; r < 4; ++r) mO[base + n * 4 + r] = oacc[n][r];
    mML[((w - 4) * 64 + lane) * 2 + 0] = mq;
    mML[((w - 4) * 64 + lane) * 2 + 1] = lsum;
  }
  __syncthreads();
  if (w < 4) {
    float mB = mML[(w * 64 + lane) * 2 + 0];
    float lB = mML[(w * 64 + lane) * 2 + 1];
    float mS = fmaxf(mq, mB);
    float fA = __expf(mq - mS), fB = __expf(mB - mS);
    float linv = 1.0f / (lsum * fA + lB * fB);
    float cAv = fA * linv, cBv = fB * linv;
    float cA[4], cB[4];
    #pragma unroll
    for (int r = 0; r < 4; ++r) {
      cA[r] = __shfl(cAv, lq * 4 + r);
      cB[r] = __shfl(cBv, lq * 4 + r);
    }
    int base = (w * 64 + lane) * 16;
    #pragma unroll
    for (int r = 0; r < 4; ++r) {
      int qr = i0 + qg * 16 + lq * 4 + r;
      #pragma unroll
      for (int n = 0; n < 4; ++n) {
        float v = oacc[n][r] * cA[r] + mO[base + n * 4 + r] * cB[r];
        ushort hb = f2bf(v);
        size_t o = ((size_t)b * 1024 + qr) * 512 + h * 64 + n * 16 + l16;
        Oh[o] = hb;
        Ol[o] = f2bf(v - bf2f(hb));
      }
    }
  }
}

// ---------------------------------------------------------------------------
extern "C" void kernel_launch(void* const* d_in, const int* in_sizes, int n_in,
                              void* d_out, int out_size, void* d_ws, size_t ws_size,
                              hipStream_t stream) {
  const float* x     = (const float*)d_in[0];
  const float* q_w   = (const float*)d_in[1];
  const float* q_b   = (const float*)d_in[2];
  const float* k_w   = (const float*)d_in[3];
  const float* k_b   = (const float*)d_in[4];
  const float* v_w   = (const float*)d_in[5];
  const float* v_b   = (const float*)d_in[6];
  const float* o_w   = (const float*)d_in[7];
  const float* o_b   = (const float*)d_in[8];
  const float* dw_w  = (const float*)d_in[9];
  const float* dw_b  = (const float*)d_in[10];
  const float* off_w = (const float*)d_in[11];
  const float* btab  = (const float*)d_in[12];

  float* ws = (float*)d_ws;
  const size_t SZ = (size_t)4 * 1024 * 512;  // 2M elements
  float* bias = ws;                          // 1M floats (4 MB)
  float* samp = ws + 1048576;                // 65536 floats
  float* dwT  = ws + 1048576 + 65536;        // 12800 floats

  ushort* u = (ushort*)(dwT + 12800);
  ushort* Xh  = u;                 // 2M ushorts each
  ushort* Qb  = Xh + SZ;
  ushort* Kb  = Qb + SZ;
  ushort* Vb  = Kb + SZ;
  ushort* Ksb = Vb + SZ;
  ushort* Vtr = Ksb + SZ;
  ushort* Aoh = Vtr + SZ;
  ushort* Aol = Aoh + SZ;
  ushort* Wq  = Aol + SZ;          // 256K ushorts each
  ushort* Wk  = Wq + 262144;
  ushort* Wv  = Wk + 262144;
  ushort* Woh = Wv + 262144;
  ushort* Wol = Woh + 262144;

  split_hi<<<2048, 256, 0, stream>>>(x, Xh, 524288);
  prep_weights<<<1026, 256, 0, stream>>>(q_w, k_w, v_w, o_w, dw_w, Wq, Wk, Wv,
                                         Woh, Wol, dwT);

  gemm_qkv<<<dim3(24, 32), 256, 0, stream>>>(Xh, Wq, Wk, Wv, q_b, k_b, v_b,
                                             Qb, Kb, Vb);

  offset_net2<<<dim3(2, 32, 4), 256, 0, stream>>>(x, dwT, dw_b, off_w, samp);
  bias_kernel<<<1024, 256, 0, stream>>>(btab, bias);
  grid_sample<<<dim3(16, 32), 256, 0, stream>>>(Kb, Vb, samp, Ksb, Vtr);

  attn_mfma<<<512, 512, 0, stream>>>(Qb, Ksb, Vtr, bias, Aoh, Aol);

  gemm_mfma<<<dim3(8, 32), 256, 0, stream>>>(Aoh, Aol, Woh, Wol, o_b,
                                             (float*)d_out);
}

// Round 10
// 109.854 us; speedup vs baseline: 1.4837x; 1.1008x over previous
//
#include <hip/hip_runtime.h>
#include <math.h>

typedef unsigned short ushort;
typedef __attribute__((ext_vector_type(8))) short bf16x8;
typedef __attribute__((ext_vector_type(4))) float f32x4;

#define MFMA16(a, b, c) __builtin_amdgcn_mfma_f32_16x16x32_bf16(a, b, c, 0, 0, 0)
#define GLOAD16(g, l)                                                   \
  __builtin_amdgcn_global_load_lds(                                     \
      (const __attribute__((address_space(1))) unsigned int*)(g),       \
      (__attribute__((address_space(3))) unsigned int*)(l), 16, 0, 0)

__device__ __forceinline__ ushort f2bf(float f) {
  unsigned u = __float_as_uint(f);
  u += 0x7FFFu + ((u >> 16) & 1u);  // RNE
  return (ushort)(u >> 16);
}
__device__ __forceinline__ float bf2f(ushort b) {
  return __uint_as_float(((unsigned)b) << 16);
}
__device__ __forceinline__ unsigned pk_bf16(float a, float b) {
  unsigned u;
  asm("v_cvt_pk_bf16_f32 %0, %1, %2" : "=v"(u) : "v"(a), "v"(b));
  return u;
}

// ---------------------------------------------------------------------------
// Fused prep: x -> bf16 (blocks 0..2047), q/k/v weights -> bf16 hi,
// o_w -> hi/lo (blocks 2048..3071), dw transpose (blocks 3072..3073).
// ---------------------------------------------------------------------------
__global__ __launch_bounds__(256) void prep_all(
    const float* __restrict__ x, const float* __restrict__ q_w,
    const float* __restrict__ k_w, const float* __restrict__ v_w,
    const float* __restrict__ o_w, const float* __restrict__ dw_w,
    ushort* __restrict__ Xh, ushort* __restrict__ Wq, ushort* __restrict__ Wk,
    ushort* __restrict__ Wv, ushort* __restrict__ Woh,
    ushort* __restrict__ Wol, float* __restrict__ dwT) {
  int blk = blockIdx.x;
  if (blk < 2048) {
    int i = blk * 256 + threadIdx.x;
    float4 v = ((const float4*)x)[i];
    ushort4 h;
    h.x = f2bf(v.x); h.y = f2bf(v.y); h.z = f2bf(v.z); h.w = f2bf(v.w);
    ((ushort4*)Xh)[i] = h;
  } else if (blk < 3072) {
    int blk2 = blk - 2048;
    int grp = blk2 >> 8;
    int i = (blk2 & 255) * 256 + threadIdx.x;
    if (grp < 3) {
      const float* in = grp == 0 ? q_w : grp == 1 ? k_w : v_w;
      ushort* hi = grp == 0 ? Wq : grp == 1 ? Wk : Wv;
      float4 v = ((const float4*)in)[i];
      ushort4 h;
      h.x = f2bf(v.x); h.y = f2bf(v.y); h.z = f2bf(v.z); h.w = f2bf(v.w);
      ((ushort4*)hi)[i] = h;
    } else {
      float4 v = ((const float4*)o_w)[i];
      ushort4 h, l;
      h.x = f2bf(v.x); l.x = f2bf(v.x - bf2f(h.x));
      h.y = f2bf(v.y); l.y = f2bf(v.y - bf2f(h.y));
      h.z = f2bf(v.z); l.z = f2bf(v.z - bf2f(h.z));
      h.w = f2bf(v.w); l.w = f2bf(v.w - bf2f(h.w));
      ((ushort4*)Woh)[i] = h;
      ((ushort4*)Wol)[i] = l;
    }
  } else {
    int c = (blk - 3072) * 256 + threadIdx.x;
    #pragma unroll
    for (int k = 0; k < 25; ++k) dwT[k * 512 + c] = dw_w[c * 25 + k];
  }
}

// ---------------------------------------------------------------------------
// Fused QKV GEMM, single-pass bf16: Yo = bf16((X@W^T + b)*scale), Q scaled.
// Tile 128x64, BK=64, 256 threads (4 waves 2x2).
// ---------------------------------------------------------------------------
__global__ __launch_bounds__(256) void gemm_qkv(
    const ushort* __restrict__ X, const ushort* __restrict__ Wq,
    const ushort* __restrict__ Wk, const ushort* __restrict__ Wv,
    const float* __restrict__ b0, const float* __restrict__ b1,
    const float* __restrict__ b2, ushort* __restrict__ Qo,
    ushort* __restrict__ Ko, ushort* __restrict__ Vo) {
  __shared__ ushort lds[12288];
  ushort* sA = lds;
  ushort* sB = lds + 8192;
  int which = blockIdx.x >> 3;
  int n0 = (blockIdx.x & 7) * 64;
  int m0 = blockIdx.y * 128;
  const ushort* W; const float* bb; ushort* Y; float scale;
  if (which == 0)      { W = Wq; bb = b0; Y = Qo; scale = 0.125f; }
  else if (which == 1) { W = Wk; bb = b1; Y = Ko; scale = 1.0f; }
  else                 { W = Wv; bb = b2; Y = Vo; scale = 1.0f; }

  int tid = threadIdx.x;
  int lane = tid & 63;
  int w = tid >> 6;
  int wr = (w >> 1) * 64;
  int wc = (w & 1) * 32;
  int l8r = lane >> 3;
  int sll = ((lane & 7) ^ l8r) << 3;
  int l16 = lane & 15, lq = lane >> 4;

  f32x4 acc[4][2];
  f32x4 zero = {0.f, 0.f, 0.f, 0.f};
  #pragma unroll
  for (int m = 0; m < 4; ++m)
    #pragma unroll
    for (int n = 0; n < 2; ++n) acc[m][n] = zero;

  for (int kt = 0; kt < 8; ++kt) {
    int kk = kt * 64;
    __syncthreads();
    #pragma unroll
    for (int q = 0; q < 4; ++q) {
      int ci = w * 4 + q;
      GLOAD16(X + (size_t)(m0 + ci * 8 + l8r) * 512 + kk + sll, sA + ci * 512);
    }
    #pragma unroll
    for (int q = 0; q < 2; ++q) {
      int ci = w * 2 + q;
      GLOAD16(W + (size_t)(n0 + ci * 8 + l8r) * 512 + kk + sll, sB + ci * 512);
    }
    __syncthreads();
    #pragma unroll
    for (int ks = 0; ks < 2; ++ks) {
      int slot = ks * 4 + lq;
      bf16x8 a[4], bvv[2];
      #pragma unroll
      for (int m = 0; m < 4; ++m) {
        int r = wr + m * 16 + l16;
        a[m] = *(const bf16x8*)&sA[r * 64 + ((slot ^ (r & 7)) << 3)];
      }
      #pragma unroll
      for (int n = 0; n < 2; ++n) {
        int r = wc + n * 16 + l16;
        bvv[n] = *(const bf16x8*)&sB[r * 64 + ((slot ^ (r & 7)) << 3)];
      }
      #pragma unroll
      for (int m = 0; m < 4; ++m)
        #pragma unroll
        for (int n = 0; n < 2; ++n)
          acc[m][n] = MFMA16(a[m], bvv[n], acc[m][n]);
    }
  }
  #pragma unroll
  for (int n = 0; n < 2; ++n) {
    int col = n0 + wc + n * 16 + l16;
    float bv = bb[col];
    #pragma unroll
    for (int m = 0; m < 4; ++m) {
      #pragma unroll
      for (int j = 0; j < 4; ++j) {
        int row = m0 + wr + m * 16 + lq * 4 + j;
        Y[(size_t)row * 512 + col] = f2bf((acc[m][n][j] + bv) * scale);
      }
    }
  }
}

// ---------------------------------------------------------------------------
// O-proj GEMM: Y[4096,512] = A_bf16 @ (Wh+Wl)^T + b, fp32 out, 2-pass.
// Tile 64x64, grid (8,64) -> 2 blocks/CU. 4 waves 2x2, each 32x32.
// ---------------------------------------------------------------------------
__global__ __launch_bounds__(256) void gemm_o(
    const ushort* __restrict__ A, const ushort* __restrict__ Wh,
    const ushort* __restrict__ Wl, const float* __restrict__ bias,
    float* __restrict__ Y) {
  __shared__ ushort sA[4096];
  __shared__ ushort sWh[4096];
  __shared__ ushort sWl[4096];
  int m0 = blockIdx.y * 64, n0 = blockIdx.x * 64;
  int tid = threadIdx.x;
  int lane = tid & 63;
  int w = tid >> 6;
  int wr = (w >> 1) * 32;
  int wc = (w & 1) * 32;
  int l8r = lane >> 3;
  int sll = ((lane & 7) ^ l8r) << 3;
  int l16 = lane & 15, lq = lane >> 4;

  f32x4 acc[2][2];
  f32x4 zero = {0.f, 0.f, 0.f, 0.f};
  #pragma unroll
  for (int m = 0; m < 2; ++m)
    #pragma unroll
    for (int n = 0; n < 2; ++n) acc[m][n] = zero;

  for (int kt = 0; kt < 8; ++kt) {
    int kk = kt * 64;
    __syncthreads();
    #pragma unroll
    for (int q = 0; q < 2; ++q) {
      int ci = w * 2 + q;
      size_t ga = (size_t)(m0 + ci * 8 + l8r) * 512 + kk + sll;
      GLOAD16(A + ga, sA + ci * 512);
      size_t gw = (size_t)(n0 + ci * 8 + l8r) * 512 + kk + sll;
      GLOAD16(Wh + gw, sWh + ci * 512);
      GLOAD16(Wl + gw, sWl + ci * 512);
    }
    __syncthreads();
    #pragma unroll
    for (int ks = 0; ks < 2; ++ks) {
      int slot = ks * 4 + lq;
      bf16x8 a[2], bh[2], bl[2];
      #pragma unroll
      for (int m = 0; m < 2; ++m) {
        int r = wr + m * 16 + l16;
        a[m] = *(const bf16x8*)&sA[r * 64 + ((slot ^ (r & 7)) << 3)];
      }
      #pragma unroll
      for (int n = 0; n < 2; ++n) {
        int r = wc + n * 16 + l16;
        int ph = (slot ^ (r & 7)) << 3;
        bh[n] = *(const bf16x8*)&sWh[r * 64 + ph];
        bl[n] = *(const bf16x8*)&sWl[r * 64 + ph];
      }
      #pragma unroll
      for (int m = 0; m < 2; ++m)
        #pragma unroll
        for (int n = 0; n < 2; ++n) {
          acc[m][n] = MFMA16(a[m], bh[n], acc[m][n]);
          acc[m][n] = MFMA16(a[m], bl[n], acc[m][n]);
        }
    }
  }
  #pragma unroll
  for (int n = 0; n < 2; ++n) {
    int col = n0 + wc + n * 16 + l16;
    float bv = bias[col];
    #pragma unroll
    for (int m = 0; m < 2; ++m) {
      #pragma unroll
      for (int j = 0; j < 4; ++j) {
        int row = m0 + wr + m * 16 + lq * 4 + j;
        Y[(size_t)row * 512 + col] = acc[m][n][j] + bv;
      }
    }
  }
}

// ---------------------------------------------------------------------------
// Offset network (register sliding-window depthwise conv). Unchanged.
// ---------------------------------------------------------------------------
__global__ __launch_bounds__(256) void offset_net2(
    const float* __restrict__ x, const float* __restrict__ dwT,
    const float* __restrict__ dw_b, const float* __restrict__ off_w,
    float* __restrict__ samp) {
  __shared__ float wT[16][516];
  __shared__ float hT[16][516];
  __shared__ float ofs[16][16];
  int x0 = blockIdx.x * 16;
  int y = blockIdx.y;
  int b = blockIdx.z;
  int tid = threadIdx.x;

  for (int e = tid; e < 2048; e += 256) {
    int o = e >> 7, c4 = e & 127;
    *(float4*)&wT[o][c4 * 4] = *(const float4*)&off_w[o * 512 + c4 * 4];
  }

  int c = tid * 2;
  float2 dwv[25];
  #pragma unroll
  for (int k = 0; k < 25; ++k) dwv[k] = *(const float2*)&dwT[k * 512 + c];
  float2 cb = *(const float2*)&dw_b[c];

  const float* xb = x + (size_t)b * 1024 * 512 + c;
  bool rv[5];
  #pragma unroll
  for (int r = 0; r < 5; ++r) {
    int yy = y - 2 + r;
    rv[r] = (yy >= 0 && yy < 32);
  }
  float2 win[5][5];
  #pragma unroll
  for (int j = 0; j < 4; ++j) {
    int xc = x0 - 2 + j;
    bool cvld = (xc >= 0 && xc < 32);
    #pragma unroll
    for (int r = 0; r < 5; ++r) {
      win[r][j] = (rv[r] && cvld)
          ? *(const float2*)&xb[(size_t)((y - 2 + r) * 32 + xc) * 512]
          : make_float2(0.f, 0.f);
    }
  }
  #pragma unroll
  for (int i = 0; i < 16; ++i) {
    int xc = x0 + i + 2;
    bool cvld = (xc < 32);
    #pragma unroll
    for (int r = 0; r < 5; ++r) {
      win[r][4] = (rv[r] && cvld)
          ? *(const float2*)&xb[(size_t)((y - 2 + r) * 32 + xc) * 512]
          : make_float2(0.f, 0.f);
    }
    float sx = cb.x, sy = cb.y;
    #pragma unroll
    for (int r = 0; r < 5; ++r)
      #pragma unroll
      for (int j = 0; j < 5; ++j) {
        sx += win[r][j].x * dwv[r * 5 + j].x;
        sy += win[r][j].y * dwv[r * 5 + j].y;
      }
    float g0 = 0.5f * sx * (1.0f + erff(sx * 0.70710678118654752f));
    float g1 = 0.5f * sy * (1.0f + erff(sy * 0.70710678118654752f));
    *(float2*)&hT[i][c] = make_float2(g0, g1);
    #pragma unroll
    for (int r = 0; r < 5; ++r) {
      win[r][0] = win[r][1]; win[r][1] = win[r][2];
      win[r][2] = win[r][3]; win[r][3] = win[r][4];
    }
  }
  __syncthreads();

  {
    int o = tid & 15, px = tid >> 4;
    float acc = 0.f;
    #pragma unroll 4
    for (int c4 = 0; c4 < 128; ++c4) {
      float4 hv = *(const float4*)&hT[px][c4 * 4];
      float4 wv = *(const float4*)&wT[o][c4 * 4];
      acc += hv.x * wv.x + hv.y * wv.y + hv.z * wv.z + hv.w * wv.w;
    }
    ofs[px][o] = tanhf(acc) * 2.0f;
  }
  __syncthreads();

  if (tid < 128) {
    int px = tid >> 3, h = tid & 7;
    int n = y * 32 + x0 + px;
    float gx = -1.0f + 2.0f * (float)(x0 + px) / 31.0f;
    float gy = -1.0f + 2.0f * (float)y / 31.0f;
    float sx = fminf(fmaxf(gx + ofs[px][2 * h], -1.0f), 1.0f);
    float sy = fminf(fmaxf(gy + ofs[px][2 * h + 1], -1.0f), 1.0f);
    float2 pc;
    pc.x = (sx + 1.0f) * 16.0f - 0.5f;
    pc.y = (sy + 1.0f) * 16.0f - 0.5f;
    ((float2*)samp)[(size_t)(b * 8 + h) * 1024 + n] = pc;
  }
}

// ---------------------------------------------------------------------------
// Bilinear grid-sample of bf16 K,V -> Ks [bh][1024][64], Vt [bh][64][1024].
// ---------------------------------------------------------------------------
__global__ __launch_bounds__(256) void grid_sample(
    const ushort* __restrict__ K, const ushort* __restrict__ V,
    const float* __restrict__ samp, ushort* __restrict__ Ks,
    ushort* __restrict__ Vt) {
  __shared__ ushort sV[64][72];
  int bh = blockIdx.y;
  int b = bh >> 3, h = bh & 7;
  int jb = blockIdx.x;
  int d = threadIdx.x & 63;
  for (int p = 0; p < 16; ++p) {
    int jl = p * 4 + (threadIdx.x >> 6);
    int j = jb * 64 + jl;
    float2 pc = ((const float2*)samp)[(size_t)bh * 1024 + j];
    float gx = pc.x, gy = pc.y;
    float x0 = floorf(gx), y0 = floorf(gy);
    float aK = 0.f, aV = 0.f;
    #pragma unroll
    for (int dy = 0; dy < 2; ++dy)
      #pragma unroll
      for (int dx = 0; dx < 2; ++dx) {
        float xi = x0 + (float)dx, yi = y0 + (float)dy;
        float wgt = (1.0f - fabsf(gx - xi)) * (1.0f - fabsf(gy - yi));
        if (xi >= 0.f && xi < 32.f && yi >= 0.f && yi < 32.f) {
          size_t base = ((size_t)b * 1024 + (int)yi * 32 + (int)xi) * 512 + h * 64 + d;
          aK += bf2f(K[base]) * wgt;
          aV += bf2f(V[base]) * wgt;
        }
      }
    Ks[((size_t)bh * 1024 + j) * 64 + d] = f2bf(aK);
    sV[jl][d] = f2bf(aV);
  }
  __syncthreads();
  int dd = threadIdx.x >> 2, c4 = threadIdx.x & 3;
  bf16x8 v0, v1;
  #pragma unroll
  for (int k = 0; k < 8; ++k) v0[k] = (short)sV[c4 * 16 + k][dd];
  #pragma unroll
  for (int k = 0; k < 8; ++k) v1[k] = (short)sV[c4 * 16 + 8 + k][dd];
  size_t o = ((size_t)bh * 64 + dd) * 1024 + jb * 64 + c4 * 16;
  *(bf16x8*)&Vt[o] = v0;
  *(bf16x8*)&Vt[o + 8] = v1;
}

// ---------------------------------------------------------------------------
// Bicubic taps + dense relative-position bias [1024][1024], bf16 (2 MB).
// ---------------------------------------------------------------------------
__device__ __forceinline__ void bicubic_taps(int i, float* w, int* idx) {
  const float a = -0.75f;
  float src = ((float)i + 0.5f) * 0.0625f - 0.5f;
  float fi = floorf(src);
  int i0 = (int)fi;
  float t = src - fi;
  #pragma unroll
  for (int k = -1; k <= 2; ++k) {
    float d = fabsf(t - (float)k);
    float wv;
    if (d <= 1.0f)
      wv = ((a + 2.0f) * d - (a + 3.0f)) * d * d + 1.0f;
    else if (d < 2.0f)
      wv = a * (((d - 5.0f) * d + 8.0f) * d - 4.0f);
    else
      wv = 0.0f;
    int ic = i0 + k;
    ic = ic < 0 ? 0 : (ic > 63 ? 63 : ic);
    w[k + 1] = wv;
    idx[k + 1] = ic;
  }
}

__global__ __launch_bounds__(256) void bias_kernel(
    const float* __restrict__ table, ushort* __restrict__ bias) {
  __shared__ float tab[225];
  int i = blockIdx.x;
  int tid = threadIdx.x;
  if (tid < 225) tab[tid] = table[tid];
  __syncthreads();
  float wA[4]; int iA[4];
  bicubic_taps(i, wA, iA);
  for (int j = tid; j < 1024; j += 256) {
    float wB[4]; int iB[4];
    bicubic_taps(j, wB, iB);
    float sum = 0.f;
    #pragma unroll
    for (int ka = 0; ka < 4; ++ka) {
      int pa = iA[ka];
      int py = pa >> 3, px = pa & 7;
      float wa = wA[ka];
      #pragma unroll
      for (int kb = 0; kb < 4; ++kb) {
        int qb = iB[kb];
        int qy = qb >> 3, qx = qb & 7;
        sum += wa * wB[kb] * tab[(py - qy + 7) * 15 + (px - qx + 7)];
      }
    }
    bias[(size_t)i * 1024 + j] = f2bf(sum);
  }
}

// ---------------------------------------------------------------------------
// MFMA flash attention v7: bf16 bias, single-bf16 output. 8 waves, KV split
// in block, KVBLK=32 double-buffered, swapped QK^T, defer-max, setprio.
// ---------------------------------------------------------------------------
__global__ __launch_bounds__(512, 6) void attn_mfma(
    const ushort* __restrict__ Qh, const ushort* __restrict__ Ks,
    const ushort* __restrict__ Vt, const ushort* __restrict__ bias,
    ushort* __restrict__ Oh) {
  __shared__ ushort sK[2][2][2048];   // [buf][half][32 keys x 64]
  __shared__ ushort sVt[2][2][2048];  // [buf][half][64 d x 32 keys]
  __shared__ ushort sP[8][640];       // per-wave [16 q][40]

  int tid = threadIdx.x;
  int lane = tid & 63;
  int w = tid >> 6;        // 0..7
  int qg = w & 3;          // query group (16 q)
  int kvh = w >> 2;        // KV half
  int l16 = lane & 15, lq = lane >> 4;
  int blk = blockIdx.x;
  int xcd = blk & 7;
  int rr = blk >> 3;
  int bh = ((rr & 3) << 3) + xcd;
  int i0 = (rr >> 2) * 64;
  int b = bh >> 3, h = bh & 7;

  // Q fragments: direct bf16 loads (pre-scaled by 0.125 in gemm_qkv)
  bf16x8 qh[2];
  #pragma unroll
  for (int s = 0; s < 2; ++s)
    qh[s] = *(const bf16x8*)&Qh[((size_t)b * 1024 + i0 + qg * 16 + l16) * 512 +
                                h * 64 + s * 32 + lq * 8];

  f32x4 oacc[4];
  f32x4 zero = {0.f, 0.f, 0.f, 0.f};
  #pragma unroll
  for (int n = 0; n < 4; ++n) oacc[n] = zero;
  float mq = -INFINITY, lsum = 0.f;

  ushort* myP = sP[w];
  int krow = qg * 8 + (lane >> 3);
  int kslot = (lane & 7) ^ (krow & 7);
  int vrow = qg * 16 + (lane >> 2);
  int vslot = (lane & 3) ^ (vrow & 3);
  size_t kbase = ((size_t)bh * 1024 + kvh * 512 + krow) * 64 + kslot * 8;
  size_t vbase = ((size_t)bh * 64 + vrow) * 1024 + kvh * 512 + vslot * 8;
  ushort* dK0 = &sK[0][kvh][qg * 8 * 64];  ushort* dK1 = &sK[1][kvh][qg * 8 * 64];
  ushort* dV0 = &sVt[0][kvh][qg * 16 * 32]; ushort* dV1 = &sVt[1][kvh][qg * 16 * 32];
  const ushort* bprow = bias + (size_t)(i0 + qg * 16 + l16) * 1024 + kvh * 512;

  GLOAD16(Ks + kbase, dK0);
  GLOAD16(Vt + vbase, dV0);
  ushort4 bias_c[2];
  #pragma unroll
  for (int n = 0; n < 2; ++n)
    bias_c[n] = *(const ushort4*)&bprow[n * 16 + lq * 4];
  __syncthreads();

  int cur = 0;
  for (int t = 0; t < 16; ++t) {
    if (t < 15) {
      size_t off = (size_t)(t + 1) * 32;
      GLOAD16(Ks + kbase + off * 64, cur ? dK0 : dK1);
      GLOAD16(Vt + vbase + off, cur ? dV0 : dV1);
    }
    f32x4 sacc[2];
    #pragma unroll
    for (int n = 0; n < 2; ++n) {
      sacc[n][0] = bf2f(bias_c[n].x);
      sacc[n][1] = bf2f(bias_c[n].y);
      sacc[n][2] = bf2f(bias_c[n].z);
      sacc[n][3] = bf2f(bias_c[n].w);
    }
    if (t < 15) {
      #pragma unroll
      for (int n = 0; n < 2; ++n)
        bias_c[n] = *(const ushort4*)&bprow[(t + 1) * 32 + n * 16 + lq * 4];
    }
    // SWAPPED QK^T, single pass: A = K rows, B = Q regs -> S^T
    const ushort* k_t = sK[cur][kvh];
    __builtin_amdgcn_s_setprio(1);
    #pragma unroll
    for (int ks = 0; ks < 2; ++ks) {
      int cslot = ((ks * 4 + lq) ^ (l16 & 7)) * 8;
      #pragma unroll
      for (int n = 0; n < 2; ++n) {
        bf16x8 aK = *(const bf16x8*)&k_t[(n * 16 + l16) * 64 + cslot];
        sacc[n] = MFMA16(aK, qh[ks], sacc[n]);
      }
    }
    __builtin_amdgcn_s_setprio(0);
    // softmax: lane owns 8 scores of query l16
    float mt = fmaxf(fmaxf(fmaxf(sacc[0][0], sacc[0][1]), fmaxf(sacc[0][2], sacc[0][3])),
                     fmaxf(fmaxf(sacc[1][0], sacc[1][1]), fmaxf(sacc[1][2], sacc[1][3])));
    mt = fmaxf(mt, __shfl_xor(mt, 16));
    mt = fmaxf(mt, __shfl_xor(mt, 32));
    if (!__all(mt <= mq + 8.0f)) {
      float mn = fmaxf(mq, mt);
      float sc = __expf(mq - mn);
      mq = mn;
      lsum *= sc;
      float scq[4];
      #pragma unroll
      for (int r = 0; r < 4; ++r) scq[r] = __shfl(sc, lq * 4 + r);
      #pragma unroll
      for (int n = 0; n < 4; ++n)
        #pragma unroll
        for (int r = 0; r < 4; ++r) oacc[n][r] *= scq[r];
    }
    float ts = 0.f;
    #pragma unroll
    for (int n = 0; n < 2; ++n) {
      float p0 = __expf(sacc[n][0] - mq);
      float p1 = __expf(sacc[n][1] - mq);
      float p2 = __expf(sacc[n][2] - mq);
      float p3 = __expf(sacc[n][3] - mq);
      ts += (p0 + p1) + (p2 + p3);
      uint2 u = make_uint2(pk_bf16(p0, p1), pk_bf16(p2, p3));
      *(uint2*)&myP[l16 * 40 + n * 16 + lq * 4] = u;
    }
    ts += __shfl_xor(ts, 16);
    ts += __shfl_xor(ts, 32);
    lsum += ts;
    // PV: A = P [16q][32k], B = V^T [16d][32k]
    bf16x8 pa = *(const bf16x8*)&myP[l16 * 40 + lq * 8];
    const ushort* vt_t = sVt[cur][kvh];
    __builtin_amdgcn_s_setprio(1);
    #pragma unroll
    for (int n = 0; n < 4; ++n) {
      int row = n * 16 + l16;
      bf16x8 bv = *(const bf16x8*)&vt_t[row * 32 + ((lq ^ (row & 3)) * 8)];
      oacc[n] = MFMA16(pa, bv, oacc[n]);
    }
    __builtin_amdgcn_s_setprio(0);
    __syncthreads();
    cur ^= 1;
  }

  // flash-merge of the two halves via LDS (reuse sK for O, sVt for m/l)
  float* mO = (float*)sK;    // 4 waves x 64 lanes x 16 f32 = 16 KB
  float* mML = (float*)sVt;  // 4 waves x 64 lanes x 2 f32
  if (w >= 4) {
    int base = ((w - 4) * 64 + lane) * 16;
    #pragma unroll
    for (int n = 0; n < 4; ++n)
      #pragma unroll
      for (int r = 0; r < 4; ++r) mO[base + n * 4 + r] = oacc[n][r];
    mML[((w - 4) * 64 + lane) * 2 + 0] = mq;
    mML[((w - 4) * 64 + lane) * 2 + 1] = lsum;
  }
  __syncthreads();
  if (w < 4) {
    float mB = mML[(w * 64 + lane) * 2 + 0];
    float lB = mML[(w * 64 + lane) * 2 + 1];
    float mS = fmaxf(mq, mB);
    float fA = __expf(mq - mS), fB = __expf(mB - mS);
    float linv = 1.0f / (lsum * fA + lB * fB);
    float cAv = fA * linv, cBv = fB * linv;
    float cA[4], cB[4];
    #pragma unroll
    for (int r = 0; r < 4; ++r) {
      cA[r] = __shfl(cAv, lq * 4 + r);
      cB[r] = __shfl(cBv, lq * 4 + r);
    }
    int base = (w * 64 + lane) * 16;
    #pragma unroll
    for (int r = 0; r < 4; ++r) {
      int qr = i0 + qg * 16 + lq * 4 + r;
      #pragma unroll
      for (int n = 0; n < 4; ++n) {
        float v = oacc[n][r] * cA[r] + mO[base + n * 4 + r] * cB[r];
        size_t o = ((size_t)b * 1024 + qr) * 512 + h * 64 + n * 16 + l16;
        Oh[o] = f2bf(v);
      }
    }
  }
}

// ---------------------------------------------------------------------------
extern "C" void kernel_launch(void* const* d_in, const int* in_sizes, int n_in,
                              void* d_out, int out_size, void* d_ws, size_t ws_size,
                              hipStream_t stream) {
  const float* x     = (const float*)d_in[0];
  const float* q_w   = (const float*)d_in[1];
  const float* q_b   = (const float*)d_in[2];
  const float* k_w   = (const float*)d_in[3];
  const float* k_b   = (const float*)d_in[4];
  const float* v_w   = (const float*)d_in[5];
  const float* v_b   = (const float*)d_in[6];
  const float* o_w   = (const float*)d_in[7];
  const float* o_b   = (const float*)d_in[8];
  const float* dw_w  = (const float*)d_in[9];
  const float* dw_b  = (const float*)d_in[10];
  const float* off_w = (const float*)d_in[11];
  const float* btab  = (const float*)d_in[12];

  float* ws = (float*)d_ws;
  const size_t SZ = (size_t)4 * 1024 * 512;  // 2M elements
  float* samp = ws;                          // 65536 floats
  float* dwT  = ws + 65536;                  // 12800 floats

  ushort* u = (ushort*)(dwT + 12800);
  ushort* Xh   = u;                // 2M ushorts each
  ushort* Qb   = Xh + SZ;
  ushort* Kb   = Qb + SZ;
  ushort* Vb   = Kb + SZ;
  ushort* Ksb  = Vb + SZ;
  ushort* Vtr  = Ksb + SZ;
  ushort* Aoh  = Vtr + SZ;
  ushort* biasb = Aoh + SZ;        // 1M ushorts (2 MB)
  ushort* Wq   = biasb + 1048576;  // 256K ushorts each
  ushort* Wk   = Wq + 262144;
  ushort* Wv   = Wk + 262144;
  ushort* Woh  = Wv + 262144;
  ushort* Wol  = Woh + 262144;

  prep_all<<<3074, 256, 0, stream>>>(x, q_w, k_w, v_w, o_w, dw_w, Xh, Wq, Wk,
                                     Wv, Woh, Wol, dwT);

  gemm_qkv<<<dim3(24, 32), 256, 0, stream>>>(Xh, Wq, Wk, Wv, q_b, k_b, v_b,
                                             Qb, Kb, Vb);

  offset_net2<<<dim3(2, 32, 4), 256, 0, stream>>>(x, dwT, dw_b, off_w, samp);
  bias_kernel<<<1024, 256, 0, stream>>>(btab, biasb);
  grid_sample<<<dim3(16, 32), 256, 0, stream>>>(Kb, Vb, samp, Ksb, Vtr);

  attn_mfma<<<512, 512, 0, stream>>>(Qb, Ksb, Vtr, biasb, Aoh);

  gemm_o<<<dim3(8, 64), 256, 0, stream>>>(Aoh, Woh, Wol, o_b, (float*)d_out);
}

// Round 11
// 103.585 us; speedup vs baseline: 1.5734x; 1.0605x over previous
//
#include <hip/hip_runtime.h>
#include <math.h>

typedef unsigned short ushort;
typedef __attribute__((ext_vector_type(8))) short bf16x8;
typedef __attribute__((ext_vector_type(4))) float f32x4;

#define MFMA16(a, b, c) __builtin_amdgcn_mfma_f32_16x16x32_bf16(a, b, c, 0, 0, 0)
#define GLOAD16(g, l)                                                   \
  __builtin_amdgcn_global_load_lds(                                     \
      (const __attribute__((address_space(1))) unsigned int*)(g),       \
      (__attribute__((address_space(3))) unsigned int*)(l), 16, 0, 0)

__device__ __forceinline__ ushort f2bf(float f) {
  unsigned u = __float_as_uint(f);
  u += 0x7FFFu + ((u >> 16) & 1u);  // RNE
  return (ushort)(u >> 16);
}
__device__ __forceinline__ float bf2f(ushort b) {
  return __uint_as_float(((unsigned)b) << 16);
}
__device__ __forceinline__ unsigned pk_bf16(float a, float b) {
  unsigned u;
  asm("v_cvt_pk_bf16_f32 %0, %1, %2" : "=v"(u) : "v"(a), "v"(b));
  return u;
}

__device__ __forceinline__ void bicubic_taps(int i, float* w, int* idx) {
  const float a = -0.75f;
  float src = ((float)i + 0.5f) * 0.0625f - 0.5f;
  float fi = floorf(src);
  int i0 = (int)fi;
  float t = src - fi;
  #pragma unroll
  for (int k = -1; k <= 2; ++k) {
    float d = fabsf(t - (float)k);
    float wv;
    if (d <= 1.0f)
      wv = ((a + 2.0f) * d - (a + 3.0f)) * d * d + 1.0f;
    else if (d < 2.0f)
      wv = a * (((d - 5.0f) * d + 8.0f) * d - 4.0f);
    else
      wv = 0.0f;
    int ic = i0 + k;
    ic = ic < 0 ? 0 : (ic > 63 ? 63 : ic);
    w[k + 1] = wv;
    idx[k + 1] = ic;
  }
}

// ---------------------------------------------------------------------------
// stage1: fused independent front-end.
//   blocks [0,1024)    : bias (bicubic-upsampled rel-pos bias -> bf16)
//   blocks [1024,1280) : offset network (dw conv -> GELU -> 1x1 -> tanh -> samp)
//   blocks [1280,3328) : x -> bf16
//   blocks [3328,4352) : q/k/v weights -> bf16 hi; o_w -> hi/lo
// One 67KB LDS pool aliased per branch.
// ---------------------------------------------------------------------------
__global__ __launch_bounds__(256) void stage1(
    const float* __restrict__ x, const float* __restrict__ q_w,
    const float* __restrict__ k_w, const float* __restrict__ v_w,
    const float* __restrict__ o_w, const float* __restrict__ dw_w,
    const float* __restrict__ dw_b, const float* __restrict__ off_w,
    const float* __restrict__ btab, ushort* __restrict__ Xh,
    ushort* __restrict__ Wq, ushort* __restrict__ Wk, ushort* __restrict__ Wv,
    ushort* __restrict__ Woh, ushort* __restrict__ Wol,
    float* __restrict__ samp, ushort* __restrict__ biasb) {
  __shared__ float smem[16768];  // 67 KB pool
  int blk = blockIdx.x;
  int tid = threadIdx.x;

  if (blk < 1024) {
    // ---- bias branch ----
    float* tab = smem;  // 225 floats
    int i = blk;
    if (tid < 225) tab[tid] = btab[tid];
    __syncthreads();
    float wA[4]; int iA[4];
    bicubic_taps(i, wA, iA);
    for (int j = tid; j < 1024; j += 256) {
      float wB[4]; int iB[4];
      bicubic_taps(j, wB, iB);
      float sum = 0.f;
      #pragma unroll
      for (int ka = 0; ka < 4; ++ka) {
        int pa = iA[ka];
        int py = pa >> 3, px = pa & 7;
        float wa = wA[ka];
        #pragma unroll
        for (int kb = 0; kb < 4; ++kb) {
          int qb = iB[kb];
          int qy = qb >> 3, qx = qb & 7;
          sum += wa * wB[kb] * tab[(py - qy + 7) * 15 + (px - qx + 7)];
        }
      }
      biasb[(size_t)i * 1024 + j] = f2bf(sum);
    }
  } else if (blk < 1280) {
    // ---- offset-network branch ----
    float* wT = smem;            // [16][516]
    float* hT = smem + 8256;     // [16][516]
    float* ofs = smem + 16512;   // [16][16]
    int ob = blk - 1024;
    int x0 = (ob & 1) * 16;
    int y = (ob >> 1) & 31;
    int b = ob >> 6;

    for (int e = tid; e < 2048; e += 256) {
      int o = e >> 7, c4 = e & 127;
      *(float4*)&wT[o * 516 + c4 * 4] = *(const float4*)&off_w[o * 512 + c4 * 4];
    }

    int c = tid * 2;
    float2 dwv[25];
    #pragma unroll
    for (int k = 0; k < 25; ++k) {
      dwv[k].x = dw_w[(size_t)c * 25 + k];
      dwv[k].y = dw_w[(size_t)(c + 1) * 25 + k];
    }
    float2 cb = *(const float2*)&dw_b[c];

    const float* xb = x + (size_t)b * 1024 * 512 + c;
    bool rv[5];
    #pragma unroll
    for (int r = 0; r < 5; ++r) {
      int yy = y - 2 + r;
      rv[r] = (yy >= 0 && yy < 32);
    }
    float2 win[5][5];
    #pragma unroll
    for (int j = 0; j < 4; ++j) {
      int xc = x0 - 2 + j;
      bool cvld = (xc >= 0 && xc < 32);
      #pragma unroll
      for (int r = 0; r < 5; ++r) {
        win[r][j] = (rv[r] && cvld)
            ? *(const float2*)&xb[(size_t)((y - 2 + r) * 32 + xc) * 512]
            : make_float2(0.f, 0.f);
      }
    }
    #pragma unroll
    for (int i = 0; i < 16; ++i) {
      int xc = x0 + i + 2;
      bool cvld = (xc < 32);
      #pragma unroll
      for (int r = 0; r < 5; ++r) {
        win[r][4] = (rv[r] && cvld)
            ? *(const float2*)&xb[(size_t)((y - 2 + r) * 32 + xc) * 512]
            : make_float2(0.f, 0.f);
      }
      float sx = cb.x, sy = cb.y;
      #pragma unroll
      for (int r = 0; r < 5; ++r)
        #pragma unroll
        for (int j = 0; j < 5; ++j) {
          sx += win[r][j].x * dwv[r * 5 + j].x;
          sy += win[r][j].y * dwv[r * 5 + j].y;
        }
      float g0 = 0.5f * sx * (1.0f + erff(sx * 0.70710678118654752f));
      float g1 = 0.5f * sy * (1.0f + erff(sy * 0.70710678118654752f));
      *(float2*)&hT[i * 516 + c] = make_float2(g0, g1);
      #pragma unroll
      for (int r = 0; r < 5; ++r) {
        win[r][0] = win[r][1]; win[r][1] = win[r][2];
        win[r][2] = win[r][3]; win[r][3] = win[r][4];
      }
    }
    __syncthreads();
    {
      int o = tid & 15, px = tid >> 4;
      float acc = 0.f;
      #pragma unroll 4
      for (int c4 = 0; c4 < 128; ++c4) {
        float4 hv = *(const float4*)&hT[px * 516 + c4 * 4];
        float4 wv = *(const float4*)&wT[o * 516 + c4 * 4];
        acc += hv.x * wv.x + hv.y * wv.y + hv.z * wv.z + hv.w * wv.w;
      }
      ofs[px * 16 + o] = tanhf(acc) * 2.0f;
    }
    __syncthreads();
    if (tid < 128) {
      int px = tid >> 3, h = tid & 7;
      int n = y * 32 + x0 + px;
      float gx = -1.0f + 2.0f * (float)(x0 + px) / 31.0f;
      float gy = -1.0f + 2.0f * (float)y / 31.0f;
      float sx = fminf(fmaxf(gx + ofs[px * 16 + 2 * h], -1.0f), 1.0f);
      float sy = fminf(fmaxf(gy + ofs[px * 16 + 2 * h + 1], -1.0f), 1.0f);
      float2 pc;
      pc.x = (sx + 1.0f) * 16.0f - 0.5f;
      pc.y = (sy + 1.0f) * 16.0f - 0.5f;
      ((float2*)samp)[(size_t)(b * 8 + h) * 1024 + n] = pc;
    }
  } else if (blk < 3328) {
    // ---- x -> bf16 ----
    int i = (blk - 1280) * 256 + tid;
    float4 v = ((const float4*)x)[i];
    ushort4 h;
    h.x = f2bf(v.x); h.y = f2bf(v.y); h.z = f2bf(v.z); h.w = f2bf(v.w);
    ((ushort4*)Xh)[i] = h;
  } else {
    // ---- weights ----
    int blk2 = blk - 3328;
    int grp = blk2 >> 8;
    int i = (blk2 & 255) * 256 + tid;
    if (grp < 3) {
      const float* in = grp == 0 ? q_w : grp == 1 ? k_w : v_w;
      ushort* hi = grp == 0 ? Wq : grp == 1 ? Wk : Wv;
      float4 v = ((const float4*)in)[i];
      ushort4 h;
      h.x = f2bf(v.x); h.y = f2bf(v.y); h.z = f2bf(v.z); h.w = f2bf(v.w);
      ((ushort4*)hi)[i] = h;
    } else {
      float4 v = ((const float4*)o_w)[i];
      ushort4 h, l;
      h.x = f2bf(v.x); l.x = f2bf(v.x - bf2f(h.x));
      h.y = f2bf(v.y); l.y = f2bf(v.y - bf2f(h.y));
      h.z = f2bf(v.z); l.z = f2bf(v.z - bf2f(h.z));
      h.w = f2bf(v.w); l.w = f2bf(v.w - bf2f(h.w));
      ((ushort4*)Woh)[i] = h;
      ((ushort4*)Wol)[i] = l;
    }
  }
}

// ---------------------------------------------------------------------------
// Fused QKV GEMM, single-pass bf16: Yo = bf16((X@W^T + b)*scale), Q scaled.
// ---------------------------------------------------------------------------
__global__ __launch_bounds__(256) void gemm_qkv(
    const ushort* __restrict__ X, const ushort* __restrict__ Wq,
    const ushort* __restrict__ Wk, const ushort* __restrict__ Wv,
    const float* __restrict__ b0, const float* __restrict__ b1,
    const float* __restrict__ b2, ushort* __restrict__ Qo,
    ushort* __restrict__ Ko, ushort* __restrict__ Vo) {
  __shared__ ushort lds[12288];
  ushort* sA = lds;
  ushort* sB = lds + 8192;
  int which = blockIdx.x >> 3;
  int n0 = (blockIdx.x & 7) * 64;
  int m0 = blockIdx.y * 128;
  const ushort* W; const float* bb; ushort* Y; float scale;
  if (which == 0)      { W = Wq; bb = b0; Y = Qo; scale = 0.125f; }
  else if (which == 1) { W = Wk; bb = b1; Y = Ko; scale = 1.0f; }
  else                 { W = Wv; bb = b2; Y = Vo; scale = 1.0f; }

  int tid = threadIdx.x;
  int lane = tid & 63;
  int w = tid >> 6;
  int wr = (w >> 1) * 64;
  int wc = (w & 1) * 32;
  int l8r = lane >> 3;
  int sll = ((lane & 7) ^ l8r) << 3;
  int l16 = lane & 15, lq = lane >> 4;

  f32x4 acc[4][2];
  f32x4 zero = {0.f, 0.f, 0.f, 0.f};
  #pragma unroll
  for (int m = 0; m < 4; ++m)
    #pragma unroll
    for (int n = 0; n < 2; ++n) acc[m][n] = zero;

  for (int kt = 0; kt < 8; ++kt) {
    int kk = kt * 64;
    __syncthreads();
    #pragma unroll
    for (int q = 0; q < 4; ++q) {
      int ci = w * 4 + q;
      GLOAD16(X + (size_t)(m0 + ci * 8 + l8r) * 512 + kk + sll, sA + ci * 512);
    }
    #pragma unroll
    for (int q = 0; q < 2; ++q) {
      int ci = w * 2 + q;
      GLOAD16(W + (size_t)(n0 + ci * 8 + l8r) * 512 + kk + sll, sB + ci * 512);
    }
    __syncthreads();
    #pragma unroll
    for (int ks = 0; ks < 2; ++ks) {
      int slot = ks * 4 + lq;
      bf16x8 a[4], bvv[2];
      #pragma unroll
      for (int m = 0; m < 4; ++m) {
        int r = wr + m * 16 + l16;
        a[m] = *(const bf16x8*)&sA[r * 64 + ((slot ^ (r & 7)) << 3)];
      }
      #pragma unroll
      for (int n = 0; n < 2; ++n) {
        int r = wc + n * 16 + l16;
        bvv[n] = *(const bf16x8*)&sB[r * 64 + ((slot ^ (r & 7)) << 3)];
      }
      #pragma unroll
      for (int m = 0; m < 4; ++m)
        #pragma unroll
        for (int n = 0; n < 2; ++n)
          acc[m][n] = MFMA16(a[m], bvv[n], acc[m][n]);
    }
  }
  #pragma unroll
  for (int n = 0; n < 2; ++n) {
    int col = n0 + wc + n * 16 + l16;
    float bv = bb[col];
    #pragma unroll
    for (int m = 0; m < 4; ++m) {
      #pragma unroll
      for (int j = 0; j < 4; ++j) {
        int row = m0 + wr + m * 16 + lq * 4 + j;
        Y[(size_t)row * 512 + col] = f2bf((acc[m][n][j] + bv) * scale);
      }
    }
  }
}

// ---------------------------------------------------------------------------
// O-proj GEMM: Y[4096,512] = A_bf16 @ (Wh+Wl)^T + b, fp32 out, 2-pass.
// Tile 64x64, grid (8,64) -> 2 blocks/CU.
// ---------------------------------------------------------------------------
__global__ __launch_bounds__(256) void gemm_o(
    const ushort* __restrict__ A, const ushort* __restrict__ Wh,
    const ushort* __restrict__ Wl, const float* __restrict__ bias,
    float* __restrict__ Y) {
  __shared__ ushort sA[4096];
  __shared__ ushort sWh[4096];
  __shared__ ushort sWl[4096];
  int m0 = blockIdx.y * 64, n0 = blockIdx.x * 64;
  int tid = threadIdx.x;
  int lane = tid & 63;
  int w = tid >> 6;
  int wr = (w >> 1) * 32;
  int wc = (w & 1) * 32;
  int l8r = lane >> 3;
  int sll = ((lane & 7) ^ l8r) << 3;
  int l16 = lane & 15, lq = lane >> 4;

  f32x4 acc[2][2];
  f32x4 zero = {0.f, 0.f, 0.f, 0.f};
  #pragma unroll
  for (int m = 0; m < 2; ++m)
    #pragma unroll
    for (int n = 0; n < 2; ++n) acc[m][n] = zero;

  for (int kt = 0; kt < 8; ++kt) {
    int kk = kt * 64;
    __syncthreads();
    #pragma unroll
    for (int q = 0; q < 2; ++q) {
      int ci = w * 2 + q;
      size_t ga = (size_t)(m0 + ci * 8 + l8r) * 512 + kk + sll;
      GLOAD16(A + ga, sA + ci * 512);
      size_t gw = (size_t)(n0 + ci * 8 + l8r) * 512 + kk + sll;
      GLOAD16(Wh + gw, sWh + ci * 512);
      GLOAD16(Wl + gw, sWl + ci * 512);
    }
    __syncthreads();
    #pragma unroll
    for (int ks = 0; ks < 2; ++ks) {
      int slot = ks * 4 + lq;
      bf16x8 a[2], bh[2], bl[2];
      #pragma unroll
      for (int m = 0; m < 2; ++m) {
        int r = wr + m * 16 + l16;
        a[m] = *(const bf16x8*)&sA[r * 64 + ((slot ^ (r & 7)) << 3)];
      }
      #pragma unroll
      for (int n = 0; n < 2; ++n) {
        int r = wc + n * 16 + l16;
        int ph = (slot ^ (r & 7)) << 3;
        bh[n] = *(const bf16x8*)&sWh[r * 64 + ph];
        bl[n] = *(const bf16x8*)&sWl[r * 64 + ph];
      }
      #pragma unroll
      for (int m = 0; m < 2; ++m)
        #pragma unroll
        for (int n = 0; n < 2; ++n) {
          acc[m][n] = MFMA16(a[m], bh[n], acc[m][n]);
          acc[m][n] = MFMA16(a[m], bl[n], acc[m][n]);
        }
    }
  }
  #pragma unroll
  for (int n = 0; n < 2; ++n) {
    int col = n0 + wc + n * 16 + l16;
    float bv = bias[col];
    #pragma unroll
    for (int m = 0; m < 2; ++m) {
      #pragma unroll
      for (int j = 0; j < 4; ++j) {
        int row = m0 + wr + m * 16 + lq * 4 + j;
        Y[(size_t)row * 512 + col] = acc[m][n][j] + bv;
      }
    }
  }
}

// ---------------------------------------------------------------------------
// Bilinear grid-sample of bf16 K,V -> Ks [bh][1024][64], Vt [bh][64][1024].
// ---------------------------------------------------------------------------
__global__ __launch_bounds__(256) void grid_sample(
    const ushort* __restrict__ K, const ushort* __restrict__ V,
    const float* __restrict__ samp, ushort* __restrict__ Ks,
    ushort* __restrict__ Vt) {
  __shared__ ushort sV[64][72];
  int bh = blockIdx.y;
  int b = bh >> 3, h = bh & 7;
  int jb = blockIdx.x;
  int d = threadIdx.x & 63;
  for (int p = 0; p < 16; ++p) {
    int jl = p * 4 + (threadIdx.x >> 6);
    int j = jb * 64 + jl;
    float2 pc = ((const float2*)samp)[(size_t)bh * 1024 + j];
    float gx = pc.x, gy = pc.y;
    float x0 = floorf(gx), y0 = floorf(gy);
    float aK = 0.f, aV = 0.f;
    #pragma unroll
    for (int dy = 0; dy < 2; ++dy)
      #pragma unroll
      for (int dx = 0; dx < 2; ++dx) {
        float xi = x0 + (float)dx, yi = y0 + (float)dy;
        float wgt = (1.0f - fabsf(gx - xi)) * (1.0f - fabsf(gy - yi));
        if (xi >= 0.f && xi < 32.f && yi >= 0.f && yi < 32.f) {
          size_t base = ((size_t)b * 1024 + (int)yi * 32 + (int)xi) * 512 + h * 64 + d;
          aK += bf2f(K[base]) * wgt;
          aV += bf2f(V[base]) * wgt;
        }
      }
    Ks[((size_t)bh * 1024 + j) * 64 + d] = f2bf(aK);
    sV[jl][d] = f2bf(aV);
  }
  __syncthreads();
  int dd = threadIdx.x >> 2, c4 = threadIdx.x & 3;
  bf16x8 v0, v1;
  #pragma unroll
  for (int k = 0; k < 8; ++k) v0[k] = (short)sV[c4 * 16 + k][dd];
  #pragma unroll
  for (int k = 0; k < 8; ++k) v1[k] = (short)sV[c4 * 16 + 8 + k][dd];
  size_t o = ((size_t)bh * 64 + dd) * 1024 + jb * 64 + c4 * 16;
  *(bf16x8*)&Vt[o] = v0;
  *(bf16x8*)&Vt[o + 8] = v1;
}

// ---------------------------------------------------------------------------
// MFMA flash attention v7 (unchanged from round 10).
// ---------------------------------------------------------------------------
__global__ __launch_bounds__(512, 6) void attn_mfma(
    const ushort* __restrict__ Qh, const ushort* __restrict__ Ks,
    const ushort* __restrict__ Vt, const ushort* __restrict__ bias,
    ushort* __restrict__ Oh) {
  __shared__ ushort sK[2][2][2048];   // [buf][half][32 keys x 64]
  __shared__ ushort sVt[2][2][2048];  // [buf][half][64 d x 32 keys]
  __shared__ ushort sP[8][640];       // per-wave [16 q][40]

  int tid = threadIdx.x;
  int lane = tid & 63;
  int w = tid >> 6;
  int qg = w & 3;
  int kvh = w >> 2;
  int l16 = lane & 15, lq = lane >> 4;
  int blk = blockIdx.x;
  int xcd = blk & 7;
  int rr = blk >> 3;
  int bh = ((rr & 3) << 3) + xcd;
  int i0 = (rr >> 2) * 64;
  int b = bh >> 3, h = bh & 7;

  bf16x8 qh[2];
  #pragma unroll
  for (int s = 0; s < 2; ++s)
    qh[s] = *(const bf16x8*)&Qh[((size_t)b * 1024 + i0 + qg * 16 + l16) * 512 +
                                h * 64 + s * 32 + lq * 8];

  f32x4 oacc[4];
  f32x4 zero = {0.f, 0.f, 0.f, 0.f};
  #pragma unroll
  for (int n = 0; n < 4; ++n) oacc[n] = zero;
  float mq = -INFINITY, lsum = 0.f;

  ushort* myP = sP[w];
  int krow = qg * 8 + (lane >> 3);
  int kslot = (lane & 7) ^ (krow & 7);
  int vrow = qg * 16 + (lane >> 2);
  int vslot = (lane & 3) ^ (vrow & 3);
  size_t kbase = ((size_t)bh * 1024 + kvh * 512 + krow) * 64 + kslot * 8;
  size_t vbase = ((size_t)bh * 64 + vrow) * 1024 + kvh * 512 + vslot * 8;
  ushort* dK0 = &sK[0][kvh][qg * 8 * 64];  ushort* dK1 = &sK[1][kvh][qg * 8 * 64];
  ushort* dV0 = &sVt[0][kvh][qg * 16 * 32]; ushort* dV1 = &sVt[1][kvh][qg * 16 * 32];
  const ushort* bprow = bias + (size_t)(i0 + qg * 16 + l16) * 1024 + kvh * 512;

  GLOAD16(Ks + kbase, dK0);
  GLOAD16(Vt + vbase, dV0);
  ushort4 bias_c[2];
  #pragma unroll
  for (int n = 0; n < 2; ++n)
    bias_c[n] = *(const ushort4*)&bprow[n * 16 + lq * 4];
  __syncthreads();

  int cur = 0;
  for (int t = 0; t < 16; ++t) {
    if (t < 15) {
      size_t off = (size_t)(t + 1) * 32;
      GLOAD16(Ks + kbase + off * 64, cur ? dK0 : dK1);
      GLOAD16(Vt + vbase + off, cur ? dV0 : dV1);
    }
    f32x4 sacc[2];
    #pragma unroll
    for (int n = 0; n < 2; ++n) {
      sacc[n][0] = bf2f(bias_c[n].x);
      sacc[n][1] = bf2f(bias_c[n].y);
      sacc[n][2] = bf2f(bias_c[n].z);
      sacc[n][3] = bf2f(bias_c[n].w);
    }
    if (t < 15) {
      #pragma unroll
      for (int n = 0; n < 2; ++n)
        bias_c[n] = *(const ushort4*)&bprow[(t + 1) * 32 + n * 16 + lq * 4];
    }
    const ushort* k_t = sK[cur][kvh];
    __builtin_amdgcn_s_setprio(1);
    #pragma unroll
    for (int ks = 0; ks < 2; ++ks) {
      int cslot = ((ks * 4 + lq) ^ (l16 & 7)) * 8;
      #pragma unroll
      for (int n = 0; n < 2; ++n) {
        bf16x8 aK = *(const bf16x8*)&k_t[(n * 16 + l16) * 64 + cslot];
        sacc[n] = MFMA16(aK, qh[ks], sacc[n]);
      }
    }
    __builtin_amdgcn_s_setprio(0);
    float mt = fmaxf(fmaxf(fmaxf(sacc[0][0], sacc[0][1]), fmaxf(sacc[0][2], sacc[0][3])),
                     fmaxf(fmaxf(sacc[1][0], sacc[1][1]), fmaxf(sacc[1][2], sacc[1][3])));
    mt = fmaxf(mt, __shfl_xor(mt, 16));
    mt = fmaxf(mt, __shfl_xor(mt, 32));
    if (!__all(mt <= mq + 8.0f)) {
      float mn = fmaxf(mq, mt);
      float sc = __expf(mq - mn);
      mq = mn;
      lsum *= sc;
      float scq[4];
      #pragma unroll
      for (int r = 0; r < 4; ++r) scq[r] = __shfl(sc, lq * 4 + r);
      #pragma unroll
      for (int n = 0; n < 4; ++n)
        #pragma unroll
        for (int r = 0; r < 4; ++r) oacc[n][r] *= scq[r];
    }
    float ts = 0.f;
    #pragma unroll
    for (int n = 0; n < 2; ++n) {
      float p0 = __expf(sacc[n][0] - mq);
      float p1 = __expf(sacc[n][1] - mq);
      float p2 = __expf(sacc[n][2] - mq);
      float p3 = __expf(sacc[n][3] - mq);
      ts += (p0 + p1) + (p2 + p3);
      uint2 u = make_uint2(pk_bf16(p0, p1), pk_bf16(p2, p3));
      *(uint2*)&myP[l16 * 40 + n * 16 + lq * 4] = u;
    }
    ts += __shfl_xor(ts, 16);
    ts += __shfl_xor(ts, 32);
    lsum += ts;
    bf16x8 pa = *(const bf16x8*)&myP[l16 * 40 + lq * 8];
    const ushort* vt_t = sVt[cur][kvh];
    __builtin_amdgcn_s_setprio(1);
    #pragma unroll
    for (int n = 0; n < 4; ++n) {
      int row = n * 16 + l16;
      bf16x8 bv = *(const bf16x8*)&vt_t[row * 32 + ((lq ^ (row & 3)) * 8)];
      oacc[n] = MFMA16(pa, bv, oacc[n]);
    }
    __builtin_amdgcn_s_setprio(0);
    __syncthreads();
    cur ^= 1;
  }

  float* mO = (float*)sK;
  float* mML = (float*)sVt;
  if (w >= 4) {
    int base = ((w - 4) * 64 + lane) * 16;
    #pragma unroll
    for (int n = 0; n < 4; ++n)
      #pragma unroll
      for (int r = 0; r < 4; ++r) mO[base + n * 4 + r] = oacc[n][r];
    mML[((w - 4) * 64 + lane) * 2 + 0] = mq;
    mML[((w - 4) * 64 + lane) * 2 + 1] = lsum;
  }
  __syncthreads();
  if (w < 4) {
    float mB = mML[(w * 64 + lane) * 2 + 0];
    float lB = mML[(w * 64 + lane) * 2 + 1];
    float mS = fmaxf(mq, mB);
    float fA = __expf(mq - mS), fB = __expf(mB - mS);
    float linv = 1.0f / (lsum * fA + lB * fB);
    float cAv = fA * linv, cBv = fB * linv;
    float cA[4], cB[4];
    #pragma unroll
    for (int r = 0; r < 4; ++r) {
      cA[r] = __shfl(cAv, lq * 4 + r);
      cB[r] = __shfl(cBv, lq * 4 + r);
    }
    int base = (w * 64 + lane) * 16;
    #pragma unroll
    for (int r = 0; r < 4; ++r) {
      int qr = i0 + qg * 16 + lq * 4 + r;
      #pragma unroll
      for (int n = 0; n < 4; ++n) {
        float v = oacc[n][r] * cA[r] + mO[base + n * 4 + r] * cB[r];
        size_t o = ((size_t)b * 1024 + qr) * 512 + h * 64 + n * 16 + l16;
        Oh[o] = f2bf(v);
      }
    }
  }
}

// ---------------------------------------------------------------------------
extern "C" void kernel_launch(void* const* d_in, const int* in_sizes, int n_in,
                              void* d_out, int out_size, void* d_ws, size_t ws_size,
                              hipStream_t stream) {
  const float* x     = (const float*)d_in[0];
  const float* q_w   = (const float*)d_in[1];
  const float* q_b   = (const float*)d_in[2];
  const float* k_w   = (const float*)d_in[3];
  const float* k_b   = (const float*)d_in[4];
  const float* v_w   = (const float*)d_in[5];
  const float* v_b   = (const float*)d_in[6];
  const float* o_w   = (const float*)d_in[7];
  const float* o_b   = (const float*)d_in[8];
  const float* dw_w  = (const float*)d_in[9];
  const float* dw_b  = (const float*)d_in[10];
  const float* off_w = (const float*)d_in[11];
  const float* btab  = (const float*)d_in[12];

  float* ws = (float*)d_ws;
  const size_t SZ = (size_t)4 * 1024 * 512;  // 2M elements
  float* samp = ws;                          // 65536 floats

  ushort* u = (ushort*)(samp + 65536);
  ushort* Xh    = u;               // 2M ushorts each
  ushort* Qb    = Xh + SZ;
  ushort* Kb    = Qb + SZ;
  ushort* Vb    = Kb + SZ;
  ushort* Ksb   = Vb + SZ;
  ushort* Vtr   = Ksb + SZ;
  ushort* Aoh   = Vtr + SZ;
  ushort* biasb = Aoh + SZ;        // 1M ushorts (2 MB)
  ushort* Wq    = biasb + 1048576; // 256K ushorts each
  ushort* Wk    = Wq + 262144;
  ushort* Wv    = Wk + 262144;
  ushort* Woh   = Wv + 262144;
  ushort* Wol   = Woh + 262144;

  stage1<<<4352, 256, 0, stream>>>(x, q_w, k_w, v_w, o_w, dw_w, dw_b, off_w,
                                   btab, Xh, Wq, Wk, Wv, Woh, Wol, samp, biasb);

  gemm_qkv<<<dim3(24, 32), 256, 0, stream>>>(Xh, Wq, Wk, Wv, q_b, k_b, v_b,
                                             Qb, Kb, Vb);

  grid_sample<<<dim3(16, 32), 256, 0, stream>>>(Kb, Vb, samp, Ksb, Vtr);

  attn_mfma<<<512, 512, 0, stream>>>(Qb, Ksb, Vtr, biasb, Aoh);

  gemm_o<<<dim3(8, 64), 256, 0, stream>>>(Aoh, Woh, Wol, o_b, (float*)d_out);
}